// Round 2
// baseline (4632.552 us; speedup 1.0000x reference)
//
#include <hip/hip_runtime.h>
#include <hip/hip_fp16.h>

#define T_STEPS 512
#define BATCH   64
#define HID     512

// Scan4 (fallback) W-row split (chunks of 8 f16 = one float4 = 4 VGPRs):
#define SCH_REG  40                 // register-resident   (160 VGPRs @ 256 budget)
#define SCH_LDS  10                 // LDS-resident        (80 KB -> 1 WG/CU!)
#define SCH_SA   7                  // streamed batch A (L2)
#define SCH_SB   7                  // streamed batch B (L2)   40+10+7+7 = 64

// Workspace layout (full path needs ~34.6 MB, unchanged):
#define X16_OFF   0u
#define X16_BYTES (16777216u * 2u)          // 32 MB bf16 x
#define WIH_OFF   (X16_OFF + X16_BYTES)
#define WIH_BYTES (262144u * 2u)            // 512 KB bf16 w_ih
#define WHH_OFF   (WIH_OFF + WIH_BYTES)
#define WHH_BYTES (262144u * 2u)            // 512 KB f16 w_hh
#define WS_FULL   (WHH_OFF + WHH_BYTES)

// Cross-block exchange buffers ALIAS the x16 region (x16 is dead after
// xproj_mfma; zero_cnt + rnn_scan5 run strictly after it on the stream).
// ex: [parity=2][b=64][slice=4][32 x u64]  = 128 KB ; cnt: 64 x u32.
#define EX_OFF    0u
#define EX_BYTES  (2u * 64u * 4u * 32u * 8u)   // 131072
#define CNT_OFF   (EX_OFF + EX_BYTES)

typedef _Float16 half2v  __attribute__((ext_vector_type(2)));
typedef short    short8  __attribute__((ext_vector_type(8)));
typedef float    f32x4   __attribute__((ext_vector_type(4)));
typedef unsigned long long u64;
union F4H  { float4 f; half2v h[4]; };
union U64H { u64 u;    half2v h[2]; };

__device__ inline float dot2f(half2v a, half2v b, float c) {
    return __builtin_amdgcn_fdot2(a, b, c, false);
}
__device__ inline unsigned short f2bf(float f) {
    unsigned u = __builtin_bit_cast(unsigned, f);
    return (unsigned short)((u + 0x7FFFu + ((u >> 16) & 1u)) >> 16);
}

// ---------------------------------------------------------------------------
// Conversions (re-run every call; ws is re-poisoned by the harness).
// ---------------------------------------------------------------------------
__global__ __launch_bounds__(256) void cvt_f16(const float* __restrict__ w,
                                               __half* __restrict__ o) {
    const int i = (blockIdx.x * 256 + threadIdx.x) * 4;
    float4 v = *(const float4*)(w + i);
    __half2 p0; p0.x = __float2half(v.x); p0.y = __float2half(v.y);
    __half2 p1; p1.x = __float2half(v.z); p1.y = __float2half(v.w);
    *(__half2*)(o + i)     = p0;
    *(__half2*)(o + i + 2) = p1;
}

__global__ __launch_bounds__(256) void cvt_bf16(const float* __restrict__ s,
                                                unsigned short* __restrict__ o) {
    const int i = (blockIdx.x * 256 + threadIdx.x) * 4;
    float4 v = *(const float4*)(s + i);
    ushort4 r = {f2bf(v.x), f2bf(v.y), f2bf(v.z), f2bf(v.w)};
    *(ushort4*)(o + i) = r;
}

__global__ void zero_cnt(unsigned* __restrict__ c) { c[threadIdx.x] = 0u; }

// ---------------------------------------------------------------------------
// xproj via bf16 MFMA (unchanged — ~140 us incl. conversions).
// ---------------------------------------------------------------------------
__global__ __launch_bounds__(256) void xproj_mfma(
    const unsigned short* __restrict__ x16,
    const unsigned short* __restrict__ w16,
    const float* __restrict__ b_ih, const float* __restrict__ b_hh,
    float* __restrict__ out)
{
    __shared__ __align__(16) unsigned short As[128][40];
    __shared__ __align__(16) unsigned short Bs[128][40];

    const int tid   = threadIdx.x;
    const int mBase = blockIdx.y * 128;
    const int nBase = blockIdx.x * 128;
    const int wave  = tid >> 6, lane = tid & 63;
    const int wy    = wave >> 1, wx = wave & 1;
    const int quad  = lane >> 4, l15 = lane & 15;
    const int lr    = tid >> 2;
    const int lk    = (tid & 3) * 8;

    f32x4 acc[4][4] = {};

    const size_t arow0 = (size_t)(mBase + lr) * 512 + lk;
    const size_t brow0 = (size_t)(nBase + lr) * 512 + lk;

    for (int k0 = 0; k0 < 512; k0 += 32) {
        int4 a0 = *(const int4*)(x16 + arow0 + k0);
        int4 a1 = *(const int4*)(x16 + arow0 + (size_t)64 * 512 + k0);
        int4 b0 = *(const int4*)(w16 + brow0 + k0);
        int4 b1 = *(const int4*)(w16 + brow0 + (size_t)64 * 512 + k0);
        __syncthreads();
        *(int4*)&As[lr][lk]      = a0;
        *(int4*)&As[lr + 64][lk] = a1;
        *(int4*)&Bs[lr][lk]      = b0;
        *(int4*)&Bs[lr + 64][lk] = b1;
        __syncthreads();

        short8 af[4], bf[4];
#pragma unroll
        for (int mt = 0; mt < 4; ++mt)
            af[mt] = *(const short8*)&As[wy * 64 + mt * 16 + l15][quad * 8];
#pragma unroll
        for (int nt = 0; nt < 4; ++nt)
            bf[nt] = *(const short8*)&Bs[wx * 64 + nt * 16 + l15][quad * 8];
#pragma unroll
        for (int mt = 0; mt < 4; ++mt)
#pragma unroll
            for (int nt = 0; nt < 4; ++nt)
                acc[mt][nt] = __builtin_amdgcn_mfma_f32_16x16x32_bf16(
                    af[mt], bf[nt], acc[mt][nt], 0, 0, 0);
    }

    float bias[4]; int coln[4];
#pragma unroll
    for (int nt = 0; nt < 4; ++nt) {
        coln[nt] = nBase + wx * 64 + nt * 16 + l15;
        bias[nt] = b_ih[coln[nt]] + b_hh[coln[nt]];
    }
#pragma unroll
    for (int mt = 0; mt < 4; ++mt)
#pragma unroll
        for (int r = 0; r < 4; ++r) {
            const int row = mBase + wy * 64 + mt * 16 + quad * 4 + r;
#pragma unroll
            for (int nt = 0; nt < 4; ++nt)
                out[(size_t)row * 512 + coln[nt]] = acc[mt][nt][r] + bias[nt];
        }
}

// ---------------------------------------------------------------------------
// Fallback fp32 xproj.
// ---------------------------------------------------------------------------
__global__ __launch_bounds__(256) void xproj_gemm(
    const float* __restrict__ x, const float* __restrict__ w_ih,
    const float* __restrict__ b_ih, const float* __restrict__ b_hh,
    float* __restrict__ out)
{
    __shared__ __align__(16) float As[16][68];
    __shared__ __align__(16) float Bs[16][68];

    const int tid   = threadIdx.x;
    const int tx    = tid & 15;
    const int ty    = tid >> 4;
    const int mBase = blockIdx.y * 64;
    const int nBase = blockIdx.x * 64;
    const int ldr   = tid >> 2;
    const int ldk   = (tid & 3) * 4;

    float acc[4][4] = {};
    const float* aptr = x    + (size_t)(mBase + ldr) * 512 + ldk;
    const float* bptr = w_ih + (size_t)(nBase + ldr) * 512 + ldk;

    for (int k0 = 0; k0 < 512; k0 += 16) {
        float4 av = *(const float4*)(aptr + k0);
        float4 bv = *(const float4*)(bptr + k0);
        __syncthreads();
        As[ldk + 0][ldr] = av.x; As[ldk + 1][ldr] = av.y;
        As[ldk + 2][ldr] = av.z; As[ldk + 3][ldr] = av.w;
        Bs[ldk + 0][ldr] = bv.x; Bs[ldk + 1][ldr] = bv.y;
        Bs[ldk + 2][ldr] = bv.z; Bs[ldk + 3][ldr] = bv.w;
        __syncthreads();
#pragma unroll
        for (int kk = 0; kk < 16; ++kk) {
            float4 a = *(const float4*)&As[kk][ty * 4];
            float4 b = *(const float4*)&Bs[kk][tx * 4];
            float ar[4] = {a.x, a.y, a.z, a.w};
            float br[4] = {b.x, b.y, b.z, b.w};
#pragma unroll
            for (int i = 0; i < 4; ++i)
#pragma unroll
                for (int j = 0; j < 4; ++j)
                    acc[i][j] = fmaf(ar[i], br[j], acc[i][j]);
        }
    }
    const int n0 = nBase + tx * 4;
    float bias[4];
#pragma unroll
    for (int j = 0; j < 4; ++j) bias[j] = b_ih[n0 + j] + b_hh[n0 + j];
#pragma unroll
    for (int i = 0; i < 4; ++i) {
        const int m = mBase + ty * 4 + i;
        float4 v = {acc[i][0] + bias[0], acc[i][1] + bias[1],
                    acc[i][2] + bias[2], acc[i][3] + bias[3]};
        *(float4*)(out + (size_t)m * 512 + n0) = v;
    }
}

// ---------------------------------------------------------------------------
// Scan v5: 4x CU parallelism. Grid = 256 blocks = 64 batches x 4 H-slices
// of 128 outputs. Thread (o = tid>>2, s = tid&3): output j = g*128+o,
// K-slice [s*128, s*128+128). W slice is fully register-resident (64 VGPR);
// h slice comes from a per-step cross-block exchange:
//   publish: packed-f16 slice (32 x 8B agent-scope atomic stores)
//   gate:    per-batch monotonic counter (atomicAdd; acquire spin >= 4(t+1))
//   reload:  32 x 8B agent-scope atomic loads (bypass stale L1/L2)
// Double-buffered ex (parity on t): the counter gate at step t transitively
// orders every sibling's read of h_{t-1} before any h_{t+1} overwrite.
// Co-residency: ~150 VGPR @ 512 thr => exactly 1 block/CU; 256 blocks on
// 256 CUs are all placed before any retires, so spins always resolve.
// blockIdx = g*64 + b keeps the 4 siblings of a batch on one XCD
// (round-robin dispatch) — performance-only assumption.
// ---------------------------------------------------------------------------
__global__ __launch_bounds__(512)
__attribute__((amdgpu_waves_per_eu(2, 2)))
void rnn_scan5(const __half* __restrict__ w16, float* __restrict__ out,
               u64* __restrict__ ex, unsigned* __restrict__ cnt)
{
    const int b   = blockIdx.x & 63;
    const int g   = blockIdx.x >> 6;
    const int tid = threadIdx.x;
    const int o   = tid >> 2;          // 0..127 output within slice
    const int s   = tid & 3;           // K-slice
    const int j   = (g << 7) + o;      // global output index

    // W[j, s*128 .. s*128+127] -> 16 float4 (64 VGPRs), register resident.
    const __half* wrow = w16 + (size_t)j * HID + (s << 7);
    float4 wreg[16];
#pragma unroll
    for (int c = 0; c < 16; ++c) wreg[c] = *(const float4*)(wrow + c * 8);

    // h K-slice registers (4 f16 per u64), h_0 = 0.
    U64H hreg[32];
#pragma unroll
    for (int c = 0; c < 32; ++c) hreg[c].u = 0ull;

    float* outb = out + (size_t)b * HID + j;
    const size_t stride = (size_t)BATCH * HID;

    unsigned* cb = cnt + b;
    u64* exw0 = ex + ((size_t)(0 * 64 + b) * 4 + g) * 32;       // write: my slice
    u64* exw1 = ex + ((size_t)(1 * 64 + b) * 4 + g) * 32;
    const u64* exr0 = ex + ((size_t)(0 * 64 + b) * 4 + s) * 32; // read: K-slice
    const u64* exr1 = ex + ((size_t)(1 * 64 + b) * 4 + s) * 32;

    float xp = (s == 0) ? outb[0] : 0.f;   // xp folded into lane s==0's partial
    float hn = 0.f;

    for (int t = 0; t < T_STEPS; ++t) {
        float a0 = xp, a1 = 0.f, a2 = 0.f, a3 = 0.f;
#pragma unroll
        for (int c = 0; c < 16; ++c) {
            F4H ww; ww.f = wreg[c];
            a0 = dot2f(ww.h[0], hreg[2 * c].h[0],     a0);
            a1 = dot2f(ww.h[1], hreg[2 * c].h[1],     a1);
            a2 = dot2f(ww.h[2], hreg[2 * c + 1].h[0], a2);
            a3 = dot2f(ww.h[3], hreg[2 * c + 1].h[1], a3);
        }
        float sum = (a0 + a1) + (a2 + a3);
        sum += __shfl_xor(sum, 1);          // DPP quad reduce over s
        sum += __shfl_xor(sum, 2);

        const float scl = fminf(fmaxf(sum, -15.f), 15.f);
        const float e   = __expf(2.f * scl);
        hn = (e - 1.f) * __builtin_amdgcn_rcpf(e + 1.f);

        if (s == 0) {
            outb[(size_t)t * stride] = hn;                       // h_t -> out
            if (t + 1 < T_STEPS) xp = outb[(size_t)(t + 1) * stride];
        }

        if (t + 1 == T_STEPS) break;       // uniform; no final exchange

        // Pack h[4m..4m+3] into one u64 on lanes tid%16==0, publish.
        unsigned hb  = (unsigned)__half_as_ushort(__float2half(hn));
        unsigned p01 = hb | (__shfl_xor(hb, 4) << 16);
        u64 quad = (u64)p01 | ((u64)__shfl_xor(p01, 8) << 32);
        if ((tid & 15) == 0) {
            u64* dst = (((t + 1) & 1) ? exw1 : exw0) + (tid >> 4);
            __hip_atomic_store(dst, quad, __ATOMIC_RELAXED,
                               __HIP_MEMORY_SCOPE_AGENT);
        }
        __syncthreads();   // every wave drains vmcnt(0): stores globally visible
        if (tid == 0) {
            atomicAdd(cb, 1u);             // device-scope, fire-and-forget
            const unsigned need = 4u * (unsigned)(t + 1);
            while (__hip_atomic_load(cb, __ATOMIC_ACQUIRE,
                                     __HIP_MEMORY_SCOPE_AGENT) < need)
                __builtin_amdgcn_s_sleep(1);
        }
        __syncthreads();

        const u64* src = ((t + 1) & 1) ? exr1 : exr0;
#pragma unroll
        for (int c = 0; c < 32; ++c)
            hreg[c].u = __hip_atomic_load(src + c, __ATOMIC_RELAXED,
                                          __HIP_MEMORY_SCOPE_AGENT);
    }

    if (s == 0)
        out[(size_t)T_STEPS * stride + (size_t)b * HID + j] = hn;   // h_n
}

// ---------------------------------------------------------------------------
// Scan v4 (mid-workspace fallback, unchanged).
// ---------------------------------------------------------------------------
#define ACC4(WF, G) do {                                        \
    F4H hh_; hh_.f = *(const float4*)(hrow + (G) * 8);          \
    F4H ww_; ww_.f = (WF);                                      \
    a0 = dot2f(ww_.h[0], hh_.h[0], a0);                         \
    a1 = dot2f(ww_.h[1], hh_.h[1], a1);                         \
    a2 = dot2f(ww_.h[2], hh_.h[2], a2);                         \
    a3 = dot2f(ww_.h[3], hh_.h[3], a3); } while (0)

__global__ __launch_bounds__(512)
__attribute__((amdgpu_waves_per_eu(2, 2)))
void rnn_scan4(const __half* __restrict__ w16, float* __restrict__ out)
{
    __shared__ __align__(16) float4 wlds[SCH_LDS][HID];
    __shared__ __align__(16) __half hbuf[2][HID];

    const int b = blockIdx.x;
    const int j = threadIdx.x;

    const __half* wrow = w16 + (size_t)j * HID;

    float4 wreg[SCH_REG];
#pragma unroll
    for (int c = 0; c < SCH_REG; ++c)
        wreg[c] = *(const float4*)(wrow + c * 8);

#pragma unroll
    for (int c = 0; c < SCH_LDS; ++c)
        wlds[c][j] = *(const float4*)(wrow + (SCH_REG + c) * 8);

    hbuf[0][j] = __float2half(0.f);
    __syncthreads();

    float* outb = out + (size_t)b * HID + j;
    const size_t stride = (size_t)BATCH * HID;
    const __half* wstr = wrow + (SCH_REG + SCH_LDS) * 8;

    int cur = 0;
    float hn = 0.f;
    float xp_next = outb[0];

    for (int t = 0; t < T_STEPS; ++t) {
        const float xp = xp_next;
        const int tn = (t + 1 < T_STEPS) ? (t + 1) : t;
        xp_next = outb[(size_t)tn * stride];

        const __half* hrow = hbuf[cur];

        float4 wa[SCH_SA];
#pragma unroll
        for (int c = 0; c < SCH_SA; ++c)
            wa[c] = *(const float4*)(wstr + c * 8);

        float a0 = xp, a1 = 0.f, a2 = 0.f, a3 = 0.f;

#pragma unroll
        for (int c = 0; c < 20; ++c) ACC4(wreg[c], c);
#pragma unroll
        for (int c = 0; c < SCH_SA; ++c)
            ACC4(wa[c], SCH_REG + SCH_LDS + c);

        float4 wb[SCH_SB];
#pragma unroll
        for (int c = 0; c < SCH_SB; ++c)
            wb[c] = *(const float4*)(wstr + (SCH_SA + c) * 8);

#pragma unroll
        for (int c = 20; c < SCH_REG; ++c) ACC4(wreg[c], c);
#pragma unroll
        for (int c = 0; c < SCH_LDS; ++c) {
            float4 wf = wlds[c][j];
            ACC4(wf, SCH_REG + c);
        }

#pragma unroll
        for (int c = 0; c < SCH_SB; ++c)
            ACC4(wb[c], SCH_REG + SCH_LDS + SCH_SA + c);

        float s = (a0 + a1) + (a2 + a3);
        s = fminf(fmaxf(s, -15.f), 15.f);
        const float e = __expf(2.f * s);
        hn = (e - 1.f) * __builtin_amdgcn_rcpf(e + 1.f);

        outb[(size_t)t * stride] = hn;
        hbuf[cur ^ 1][j] = __float2half(hn);
        __syncthreads();
        cur ^= 1;
    }
    out[(size_t)T_STEPS * stride + (size_t)b * HID + j] = hn;
}

// ---------------------------------------------------------------------------
// Last-resort fp32 scan (no workspace needed).
// ---------------------------------------------------------------------------
__global__ __launch_bounds__(512) void rnn_scan_f32(const float* __restrict__ w,
                                                    float* __restrict__ out)
{
    __shared__ __align__(16) __half hs[2][HID];
    const int b = blockIdx.x;
    const int j = threadIdx.x;

    hs[0][j] = __float2half(0.f);
    __syncthreads();

    const float* wrow32 = w + (size_t)j * HID;
    float* outb = out + (size_t)b * HID + j;
    int cur = 0;
    float hn = 0.f;

    for (int t = 0; t < T_STEPS; ++t) {
        float a0 = outb[(size_t)t * (BATCH * HID)];
        float a1 = 0.f, a2 = 0.f, a3 = 0.f;
#pragma unroll 4
        for (int k0 = 0; k0 < HID; k0 += 8) {
            float4 w0 = *(const float4*)(wrow32 + k0);
            float4 w1 = *(const float4*)(wrow32 + k0 + 4);
            F4H h; h.f = *(const float4*)(&hs[cur][k0]);
            float2 h0 = __half22float2(*(__half2*)&h.h[0]);
            float2 h1 = __half22float2(*(__half2*)&h.h[1]);
            float2 h2 = __half22float2(*(__half2*)&h.h[2]);
            float2 h3 = __half22float2(*(__half2*)&h.h[3]);
            a0 = fmaf(w0.x, h0.x, a0); a1 = fmaf(w0.y, h0.y, a1);
            a2 = fmaf(w0.z, h1.x, a2); a3 = fmaf(w0.w, h1.y, a3);
            a0 = fmaf(w1.x, h2.x, a0); a1 = fmaf(w1.y, h2.y, a1);
            a2 = fmaf(w1.z, h3.x, a2); a3 = fmaf(w1.w, h3.y, a3);
        }
        hn = tanhf((a0 + a1) + (a2 + a3));
        outb[(size_t)t * (BATCH * HID)] = hn;
        hs[cur ^ 1][j] = __float2half(hn);
        __syncthreads();
        cur ^= 1;
    }
    out[(size_t)T_STEPS * BATCH * HID + (size_t)b * HID + j] = hn;
}

// ---------------------------------------------------------------------------
extern "C" void kernel_launch(void* const* d_in, const int* in_sizes, int n_in,
                              void* d_out, int out_size, void* d_ws, size_t ws_size,
                              hipStream_t stream) {
    const float* x    = (const float*)d_in[0];
    const float* w_ih = (const float*)d_in[1];
    const float* w_hh = (const float*)d_in[2];
    const float* b_ih = (const float*)d_in[3];
    const float* b_hh = (const float*)d_in[4];
    float* out = (float*)d_out;

    char* ws = (char*)d_ws;
    const bool full = ws_size >= (size_t)WS_FULL;
    const bool mid  = ws_size >= (size_t)WHH_BYTES;

    if (full) {
        unsigned short* x16   = (unsigned short*)(ws + X16_OFF);
        unsigned short* wih16 = (unsigned short*)(ws + WIH_OFF);
        __half*         whh16 = (__half*)(ws + WHH_OFF);
        u64*            ex    = (u64*)(ws + EX_OFF);       // aliases x16 (dead)
        unsigned*       cnt   = (unsigned*)(ws + CNT_OFF); // after xproj_mfma
        cvt_bf16<<<16384, 256, 0, stream>>>(x, x16);
        cvt_bf16<<<256,   256, 0, stream>>>(w_ih, wih16);
        cvt_f16 <<<256,   256, 0, stream>>>(w_hh, whh16);
        xproj_mfma<<<dim3(4, 256), 256, 0, stream>>>(x16, wih16, b_ih, b_hh, out);
        zero_cnt<<<1, 64, 0, stream>>>(cnt);
        rnn_scan5<<<256, 512, 0, stream>>>(whh16, out, ex, cnt);
    } else if (mid) {
        __half* whh16 = (__half*)ws;
        cvt_f16<<<256, 256, 0, stream>>>(w_hh, whh16);
        xproj_gemm<<<dim3(8, 512), 256, 0, stream>>>(x, w_ih, b_ih, b_hh, out);
        rnn_scan4<<<BATCH, HID, 0, stream>>>(whh16, out);
    } else {
        xproj_gemm<<<dim3(8, 512), 256, 0, stream>>>(x, w_ih, b_ih, b_hh, out);
        rnn_scan_f32<<<BATCH, HID, 0, stream>>>(w_hh, out);
    }
}

// Round 3
// 1420.058 us; speedup vs baseline: 3.2622x; 3.2622x over previous
//
#include <hip/hip_runtime.h>
#include <hip/hip_fp16.h>

#define T_STEPS 512
#define BATCH   64
#define HID     512

// ---- scan6 geometry: grid=4 blocks x 16 batches, 8 waves x 64 rows ----
#define NB      16
#define AK_LDS  12                  // tau3 ki-chunks resident in LDS (of 16)

// ---- scan4 (fallback) W-row split ----
#define SCH_REG  40
#define SCH_LDS  10
#define SCH_SA   7
#define SCH_SB   7

// Workspace layout (same 34.6 MB total as previously granted):
//   xp16: pre-transposed f16 xproj, chunk layout (32 MB)
//   wih16: bf16 w_ih (512 KB) ; whh16: f16 w_hh (512 KB)
#define XP16_OFF  0u
#define XP16_BYTES (16777216u * 2u)         // 32 MB
#define WIH_OFF   (XP16_OFF + XP16_BYTES)
#define WIH_BYTES (262144u * 2u)
#define WHH_OFF   (WIH_OFF + WIH_BYTES)
#define WHH_BYTES (262144u * 2u)
#define WS_FULL   (WHH_OFF + WHH_BYTES)

typedef _Float16 half2v  __attribute__((ext_vector_type(2)));
typedef _Float16 half4v  __attribute__((ext_vector_type(4)));
typedef _Float16 half8   __attribute__((ext_vector_type(8)));
typedef short    short8  __attribute__((ext_vector_type(8)));
typedef float    f32x4   __attribute__((ext_vector_type(4)));
union F4H  { float4 f; half2v h[4]; };

__device__ inline float dot2f(half2v a, half2v b, float c) {
    return __builtin_amdgcn_fdot2(a, b, c, false);
}
__device__ inline unsigned short f2bf(float f) {
    unsigned u = __builtin_bit_cast(unsigned, f);
    return (unsigned short)((u + 0x7FFFu + ((u >> 16) & 1u)) >> 16);
}

// ---------------------------------------------------------------------------
// Conversions (re-run every call; ws is re-poisoned by the harness).
// ---------------------------------------------------------------------------
__global__ __launch_bounds__(256) void cvt_f16(const float* __restrict__ w,
                                               __half* __restrict__ o) {
    const int i = (blockIdx.x * 256 + threadIdx.x) * 4;
    float4 v = *(const float4*)(w + i);
    __half2 p0; p0.x = __float2half(v.x); p0.y = __float2half(v.y);
    __half2 p1; p1.x = __float2half(v.z); p1.y = __float2half(v.w);
    *(__half2*)(o + i)     = p0;
    *(__half2*)(o + i + 2) = p1;
}

__global__ __launch_bounds__(256) void cvt_bf16(const float* __restrict__ s,
                                                unsigned short* __restrict__ o) {
    const int i = (blockIdx.x * 256 + threadIdx.x) * 4;
    float4 v = *(const float4*)(s + i);
    ushort4 r = {f2bf(v.x), f2bf(v.y), f2bf(v.z), f2bf(v.w)};
    *(ushort4*)(o + i) = r;
}

// ---------------------------------------------------------------------------
// xproj via bf16 MFMA. Reads x f32 (converts in staging), writes f16 xp16
// in the scan's chunk layout:
//   half-index(t,b,o) = t*32768 + (b>>4)*8192 + (o>>3)*128 + (b&15)*8 + (o&7)
// ---------------------------------------------------------------------------
__global__ __launch_bounds__(256) void xproj_mfma(
    const float* __restrict__ x,
    const unsigned short* __restrict__ w16,
    const float* __restrict__ b_ih, const float* __restrict__ b_hh,
    __half* __restrict__ xp16)
{
    __shared__ __align__(16) unsigned short As[128][40];
    __shared__ __align__(16) unsigned short Bs[128][40];

    const int tid   = threadIdx.x;
    const int mBase = blockIdx.y * 128;
    const int nBase = blockIdx.x * 128;
    const int wave  = tid >> 6, lane = tid & 63;
    const int wy    = wave >> 1, wx = wave & 1;
    const int quad  = lane >> 4, l15 = lane & 15;
    const int lr    = tid >> 2;
    const int lk    = (tid & 3) * 8;

    f32x4 acc[4][4] = {};

    const size_t arow0 = (size_t)(mBase + lr) * 512 + lk;
    const size_t brow0 = (size_t)(nBase + lr) * 512 + lk;

    for (int k0 = 0; k0 < 512; k0 += 32) {
        float4 a0l = *(const float4*)(x + arow0 + k0);
        float4 a0h = *(const float4*)(x + arow0 + k0 + 4);
        float4 a1l = *(const float4*)(x + arow0 + (size_t)64 * 512 + k0);
        float4 a1h = *(const float4*)(x + arow0 + (size_t)64 * 512 + k0 + 4);
        int4 b0 = *(const int4*)(w16 + brow0 + k0);
        int4 b1 = *(const int4*)(w16 + brow0 + (size_t)64 * 512 + k0);
        int4 A0, A1;
        A0.x = f2bf(a0l.x) | ((unsigned)f2bf(a0l.y) << 16);
        A0.y = f2bf(a0l.z) | ((unsigned)f2bf(a0l.w) << 16);
        A0.z = f2bf(a0h.x) | ((unsigned)f2bf(a0h.y) << 16);
        A0.w = f2bf(a0h.z) | ((unsigned)f2bf(a0h.w) << 16);
        A1.x = f2bf(a1l.x) | ((unsigned)f2bf(a1l.y) << 16);
        A1.y = f2bf(a1l.z) | ((unsigned)f2bf(a1l.w) << 16);
        A1.z = f2bf(a1h.x) | ((unsigned)f2bf(a1h.y) << 16);
        A1.w = f2bf(a1h.z) | ((unsigned)f2bf(a1h.w) << 16);
        __syncthreads();
        *(int4*)&As[lr][lk]      = A0;
        *(int4*)&As[lr + 64][lk] = A1;
        *(int4*)&Bs[lr][lk]      = b0;
        *(int4*)&Bs[lr + 64][lk] = b1;
        __syncthreads();

        short8 af[4], bf[4];
#pragma unroll
        for (int mt = 0; mt < 4; ++mt)
            af[mt] = *(const short8*)&As[wy * 64 + mt * 16 + l15][quad * 8];
#pragma unroll
        for (int nt = 0; nt < 4; ++nt)
            bf[nt] = *(const short8*)&Bs[wx * 64 + nt * 16 + l15][quad * 8];
#pragma unroll
        for (int mt = 0; mt < 4; ++mt)
#pragma unroll
            for (int nt = 0; nt < 4; ++nt)
                acc[mt][nt] = __builtin_amdgcn_mfma_f32_16x16x32_bf16(
                    af[mt], bf[nt], acc[mt][nt], 0, 0, 0);
    }

    float bias[4]; int coln[4];
#pragma unroll
    for (int nt = 0; nt < 4; ++nt) {
        coln[nt] = nBase + wx * 64 + nt * 16 + l15;
        bias[nt] = b_ih[coln[nt]] + b_hh[coln[nt]];
    }
#pragma unroll
    for (int mt = 0; mt < 4; ++mt)
#pragma unroll
        for (int r = 0; r < 4; ++r) {
            const int m = mBase + wy * 64 + mt * 16 + quad * 4 + r;
            const int tt = m >> 6, b = m & 63;
#pragma unroll
            for (int nt = 0; nt < 4; ++nt) {
                const int o = coln[nt];
                const size_t idx = (size_t)tt * 32768 + (size_t)(b >> 4) * 8192
                                 + (o >> 3) * 128 + (b & 15) * 8 + (o & 7);
                xp16[idx] = __float2half(acc[mt][nt][r] + bias[nt]);
            }
        }
}

// ---------------------------------------------------------------------------
// Fallback fp32 xproj (writes f32 xproj into out, scan4-compatible).
// ---------------------------------------------------------------------------
__global__ __launch_bounds__(256) void xproj_gemm(
    const float* __restrict__ x, const float* __restrict__ w_ih,
    const float* __restrict__ b_ih, const float* __restrict__ b_hh,
    float* __restrict__ out)
{
    __shared__ __align__(16) float As[16][68];
    __shared__ __align__(16) float Bs[16][68];

    const int tid   = threadIdx.x;
    const int tx    = tid & 15;
    const int ty    = tid >> 4;
    const int mBase = blockIdx.y * 64;
    const int nBase = blockIdx.x * 64;
    const int ldr   = tid >> 2;
    const int ldk   = (tid & 3) * 4;

    float acc[4][4] = {};
    const float* aptr = x    + (size_t)(mBase + ldr) * 512 + ldk;
    const float* bptr = w_ih + (size_t)(nBase + ldr) * 512 + ldk;

    for (int k0 = 0; k0 < 512; k0 += 16) {
        float4 av = *(const float4*)(aptr + k0);
        float4 bv = *(const float4*)(bptr + k0);
        __syncthreads();
        As[ldk + 0][ldr] = av.x; As[ldk + 1][ldr] = av.y;
        As[ldk + 2][ldr] = av.z; As[ldk + 3][ldr] = av.w;
        Bs[ldk + 0][ldr] = bv.x; Bs[ldk + 1][ldr] = bv.y;
        Bs[ldk + 2][ldr] = bv.z; Bs[ldk + 3][ldr] = bv.w;
        __syncthreads();
#pragma unroll
        for (int kk = 0; kk < 16; ++kk) {
            float4 a = *(const float4*)&As[kk][ty * 4];
            float4 b = *(const float4*)&Bs[kk][tx * 4];
            float ar[4] = {a.x, a.y, a.z, a.w};
            float br[4] = {b.x, b.y, b.z, b.w};
#pragma unroll
            for (int i = 0; i < 4; ++i)
#pragma unroll
                for (int j = 0; j < 4; ++j)
                    acc[i][j] = fmaf(ar[i], br[j], acc[i][j]);
        }
    }
    const int n0 = nBase + tx * 4;
    float bias[4];
#pragma unroll
    for (int j = 0; j < 4; ++j) bias[j] = b_ih[n0 + j] + b_hh[n0 + j];
#pragma unroll
    for (int i = 0; i < 4; ++i) {
        const int m = mBase + ty * 4 + i;
        float4 v = {acc[i][0] + bias[0], acc[i][1] + bias[1],
                    acc[i][2] + bias[2], acc[i][3] + bias[3]};
        *(float4*)(out + (size_t)m * 512 + n0) = v;
    }
}

// ---------------------------------------------------------------------------
// Scan v6: MFMA scan. Grid = 4 blocks x 16 batches. 512 thr = 8 waves;
// wave w owns output rows 64w..64w+63 (4 tiles of 16 rows).
// Per step per wave: 64x mfma_f32_16x16x32_f16 (A=W rows, B=h).
//   W: tau0..2 + tau3[ki12..15] pinned in VGPRs (208); tau3[ki0..11] in LDS.
//   h: f16 in LDS chunk layout [chunk=o>>3][batch][j=o&7] -> b128 B-frags,
//      conflict-free; h-writeback 4x ds_write_b64; out-stage coalesced.
//   xp: f16, pre-transposed by xproj into the same chunk layout -> 4x 8B
//      global loads per thread per step (dense 64B lines).
// No cross-CU sync. 2 barriers/step.
// ---------------------------------------------------------------------------
#define PIN8(a) asm volatile("" : "+v"(a[0]), "+v"(a[1]), "+v"(a[2]), "+v"(a[3]), \
                                  "+v"(a[4]), "+v"(a[5]), "+v"(a[6]), "+v"(a[7]))

__global__ __launch_bounds__(512)
__attribute__((amdgpu_waves_per_eu(2, 2)))
void rnn_scan6(const __half* __restrict__ whh16,
               const __half* __restrict__ xp16,
               float* __restrict__ out)
{
    __shared__ __align__(16) _Float16 hlds[64 * NB * 8];          // 16 KB
    __shared__ __align__(16) _Float16 alds[8 * AK_LDS * 512];     // 96 KB

    const int bg   = blockIdx.x;
    const int tid  = threadIdx.x;
    const int w    = tid >> 6;
    const int lane = tid & 63;
    const int q    = lane >> 4;
    const int l15  = lane & 15;

    // ---- W fragments: row = 64w + 16*tau + l15, k = 32*ki + 8q + j ----
    const __half* wbase = whh16 + ((size_t)(64 * w + l15)) * 512 + 8 * q;
    half8 wf0[16], wf1[16], wf2[16], wf3[4];
#pragma unroll
    for (int ki = 0; ki < 16; ++ki) {
        wf0[ki] = *(const half8*)(wbase + 32 * ki);
        wf1[ki] = *(const half8*)(wbase + (size_t)16 * 512 + 32 * ki);
        wf2[ki] = *(const half8*)(wbase + (size_t)32 * 512 + 32 * ki);
    }
#pragma unroll
    for (int ki = 0; ki < 4; ++ki)
        wf3[ki] = *(const half8*)(wbase + (size_t)48 * 512 + 32 * (12 + ki));
#pragma unroll
    for (int ki = 0; ki < AK_LDS; ++ki) {
        half8 v = *(const half8*)(wbase + (size_t)48 * 512 + 32 * ki);
        *(half8*)&alds[(w * AK_LDS + ki) * 512 + lane * 8] = v;
    }
    // zero h_0
    {
        float4 z = {0.f, 0.f, 0.f, 0.f};
        *(float4*)&hlds[tid * 16]     = z;
        *(float4*)&hlds[tid * 16 + 8] = z;
    }
    __syncthreads();

    // ---- per-thread invariant indices ----
    // chunk-layout index for (o = 64w+16*tau+4q+r, batch=l15):
    //   idx = (8w+2*tau+(q>>1))*128 + l15*8 + (q&1)*4 + r    (halfs)
    int cidx[4];
#pragma unroll
    for (int ta = 0; ta < 4; ++ta)
        cidx[ta] = (8 * w + 2 * ta + (q >> 1)) * 128 + l15 * 8 + (q & 1) * 4;

    const __half* xpb = xp16 + (size_t)bg * 8192;   // + t*32768 + cidx[ta]

    // out-stage: thread handles batch sb, outputs so..so+15
    const int sb  = tid >> 5, so = (tid & 31) * 16;
    const int hrd = ((tid & 31) * 2) * 128 + sb * 8;
    float* outb = out + (size_t)(bg * 16 + sb) * 512 + so;
    const size_t ostride = (size_t)BATCH * HID;

    for (int t = 0; t < T_STEPS; ++t) {
        // xp for this step (consumed in phase B)
        uint2 xpv0 = *(const uint2*)(xpb + (size_t)t * 32768 + cidx[0]);
        uint2 xpv1 = *(const uint2*)(xpb + (size_t)t * 32768 + cidx[1]);
        uint2 xpv2 = *(const uint2*)(xpb + (size_t)t * 32768 + cidx[2]);
        uint2 xpv3 = *(const uint2*)(xpb + (size_t)t * 32768 + cidx[3]);

        // out-stage h_{t-1} (h-LDS is stable through phase A)
        if (t > 0) {
            half8 h0 = *(const half8*)&hlds[hrd];
            half8 h1 = *(const half8*)&hlds[hrd + 128];
            float* dst = outb + (size_t)(t - 1) * ostride;
            float4 v0 = {(float)h0[0], (float)h0[1], (float)h0[2], (float)h0[3]};
            float4 v1 = {(float)h0[4], (float)h0[5], (float)h0[6], (float)h0[7]};
            float4 v2 = {(float)h1[0], (float)h1[1], (float)h1[2], (float)h1[3]};
            float4 v3 = {(float)h1[4], (float)h1[5], (float)h1[6], (float)h1[7]};
            *(float4*)(dst)      = v0;
            *(float4*)(dst + 4)  = v1;
            *(float4*)(dst + 8)  = v2;
            *(float4*)(dst + 12) = v3;
        }

        // MFMA phase
        f32x4 acc0 = {0.f, 0.f, 0.f, 0.f};
        f32x4 acc1 = {0.f, 0.f, 0.f, 0.f};
        f32x4 acc2 = {0.f, 0.f, 0.f, 0.f};
        f32x4 acc3 = {0.f, 0.f, 0.f, 0.f};
#pragma unroll
        for (int ki = 0; ki < 16; ++ki) {
            half8 bfr = *(const half8*)&hlds[(4 * ki + q) * 128 + l15 * 8];
            acc0 = __builtin_amdgcn_mfma_f32_16x16x32_f16(wf0[ki], bfr, acc0, 0, 0, 0);
            acc1 = __builtin_amdgcn_mfma_f32_16x16x32_f16(wf1[ki], bfr, acc1, 0, 0, 0);
            acc2 = __builtin_amdgcn_mfma_f32_16x16x32_f16(wf2[ki], bfr, acc2, 0, 0, 0);
            half8 a3;
            if (ki < AK_LDS)
                a3 = *(const half8*)&alds[(w * AK_LDS + ki) * 512 + lane * 8];
            else
                a3 = wf3[ki - AK_LDS];
            acc3 = __builtin_amdgcn_mfma_f32_16x16x32_f16(a3, bfr, acc3, 0, 0, 0);
        }
        __syncthreads();   // barrier1: all reads of hlds done

        // phase B: xp add + tanh + h writeback
#pragma unroll
        for (int ta = 0; ta < 4; ++ta) {
            const uint2 xv = (ta == 0) ? xpv0 : (ta == 1) ? xpv1
                           : (ta == 2) ? xpv2 : xpv3;
            const half4v xh = __builtin_bit_cast(half4v, xv);
            const f32x4 A = (ta == 0) ? acc0 : (ta == 1) ? acc1
                          : (ta == 2) ? acc2 : acc3;
            half4v hv;
#pragma unroll
            for (int r = 0; r < 4; ++r) {
                float s = A[r] + (float)xh[r];
                s = fminf(fmaxf(s, -15.f), 15.f);
                const float e = __expf(2.f * s);
                hv[r] = (_Float16)((e - 1.f) * __builtin_amdgcn_rcpf(e + 1.f));
            }
            *(half4v*)&hlds[cidx[ta]] = hv;
        }
        // keep W fragments live-in-register across the loop (anti-remat)
        PIN8(wf0); PIN8((wf0 + 8)); PIN8(wf1); PIN8((wf1 + 8));
        PIN8(wf2); PIN8((wf2 + 8));
        asm volatile("" : "+v"(wf3[0]), "+v"(wf3[1]), "+v"(wf3[2]), "+v"(wf3[3]));
        __syncthreads();   // barrier2: h_t visible
    }

    // final: h_{511} -> out[511] and h_n -> out[512]
    {
        half8 h0 = *(const half8*)&hlds[hrd];
        half8 h1 = *(const half8*)&hlds[hrd + 128];
        float4 v0 = {(float)h0[0], (float)h0[1], (float)h0[2], (float)h0[3]};
        float4 v1 = {(float)h0[4], (float)h0[5], (float)h0[6], (float)h0[7]};
        float4 v2 = {(float)h1[0], (float)h1[1], (float)h1[2], (float)h1[3]};
        float4 v3 = {(float)h1[4], (float)h1[5], (float)h1[6], (float)h1[7]};
        float* d0 = outb + (size_t)(T_STEPS - 1) * ostride;
        float* d1 = outb + (size_t)T_STEPS * ostride;
        *(float4*)(d0)      = v0; *(float4*)(d0 + 4)  = v1;
        *(float4*)(d0 + 8)  = v2; *(float4*)(d0 + 12) = v3;
        *(float4*)(d1)      = v0; *(float4*)(d1 + 4)  = v1;
        *(float4*)(d1 + 8)  = v2; *(float4*)(d1 + 12) = v3;
    }
}

// ---------------------------------------------------------------------------
// Scan v4 (mid-workspace fallback; reads f32 xproj from out in-place).
// ---------------------------------------------------------------------------
#define ACC4(WF, G) do {                                        \
    F4H hh_; hh_.f = *(const float4*)(hrow + (G) * 8);          \
    F4H ww_; ww_.f = (WF);                                      \
    a0 = dot2f(ww_.h[0], hh_.h[0], a0);                         \
    a1 = dot2f(ww_.h[1], hh_.h[1], a1);                         \
    a2 = dot2f(ww_.h[2], hh_.h[2], a2);                         \
    a3 = dot2f(ww_.h[3], hh_.h[3], a3); } while (0)

__global__ __launch_bounds__(512)
__attribute__((amdgpu_waves_per_eu(2, 2)))
void rnn_scan4(const __half* __restrict__ w16, float* __restrict__ out)
{
    __shared__ __align__(16) float4 wlds[SCH_LDS][HID];
    __shared__ __align__(16) __half hbuf[2][HID];

    const int b = blockIdx.x;
    const int j = threadIdx.x;

    const __half* wrow = w16 + (size_t)j * HID;

    float4 wreg[SCH_REG];
#pragma unroll
    for (int c = 0; c < SCH_REG; ++c)
        wreg[c] = *(const float4*)(wrow + c * 8);

#pragma unroll
    for (int c = 0; c < SCH_LDS; ++c)
        wlds[c][j] = *(const float4*)(wrow + (SCH_REG + c) * 8);

    hbuf[0][j] = __float2half(0.f);
    __syncthreads();

    float* outb = out + (size_t)b * HID + j;
    const size_t stride = (size_t)BATCH * HID;
    const __half* wstr = wrow + (SCH_REG + SCH_LDS) * 8;

    int cur = 0;
    float hn = 0.f;
    float xp_next = outb[0];

    for (int t = 0; t < T_STEPS; ++t) {
        const float xp = xp_next;
        const int tn = (t + 1 < T_STEPS) ? (t + 1) : t;
        xp_next = outb[(size_t)tn * stride];

        const __half* hrow = hbuf[cur];

        float4 wa[SCH_SA];
#pragma unroll
        for (int c = 0; c < SCH_SA; ++c)
            wa[c] = *(const float4*)(wstr + c * 8);

        float a0 = xp, a1 = 0.f, a2 = 0.f, a3 = 0.f;

#pragma unroll
        for (int c = 0; c < 20; ++c) ACC4(wreg[c], c);
#pragma unroll
        for (int c = 0; c < SCH_SA; ++c)
            ACC4(wa[c], SCH_REG + SCH_LDS + c);

        float4 wb[SCH_SB];
#pragma unroll
        for (int c = 0; c < SCH_SB; ++c)
            wb[c] = *(const float4*)(wstr + (SCH_SA + c) * 8);

#pragma unroll
        for (int c = 20; c < SCH_REG; ++c) ACC4(wreg[c], c);
#pragma unroll
        for (int c = 0; c < SCH_LDS; ++c) {
            float4 wfv = wlds[c][j];
            ACC4(wfv, SCH_REG + c);
        }

#pragma unroll
        for (int c = 0; c < SCH_SB; ++c)
            ACC4(wb[c], SCH_REG + SCH_LDS + SCH_SA + c);

        float s = (a0 + a1) + (a2 + a3);
        s = fminf(fmaxf(s, -15.f), 15.f);
        const float e = __expf(2.f * s);
        hn = (e - 1.f) * __builtin_amdgcn_rcpf(e + 1.f);

        outb[(size_t)t * stride] = hn;
        hbuf[cur ^ 1][j] = __float2half(hn);
        __syncthreads();
        cur ^= 1;
    }
    out[(size_t)T_STEPS * stride + (size_t)b * HID + j] = hn;
}

// ---------------------------------------------------------------------------
// Last-resort fp32 scan (no workspace needed).
// ---------------------------------------------------------------------------
__global__ __launch_bounds__(512) void rnn_scan_f32(const float* __restrict__ w,
                                                    float* __restrict__ out)
{
    __shared__ __align__(16) __half hs[2][HID];
    const int b = blockIdx.x;
    const int j = threadIdx.x;

    hs[0][j] = __float2half(0.f);
    __syncthreads();

    const float* wrow32 = w + (size_t)j * HID;
    float* outb = out + (size_t)b * HID + j;
    int cur = 0;
    float hn = 0.f;

    for (int t = 0; t < T_STEPS; ++t) {
        float a0 = outb[(size_t)t * (BATCH * HID)];
        float a1 = 0.f, a2 = 0.f, a3 = 0.f;
#pragma unroll 4
        for (int k0 = 0; k0 < HID; k0 += 8) {
            float4 w0 = *(const float4*)(wrow32 + k0);
            float4 w1 = *(const float4*)(wrow32 + k0 + 4);
            F4H h; h.f = *(const float4*)(&hs[cur][k0]);
            float2 h0 = __half22float2(*(__half2*)&h.h[0]);
            float2 h1 = __half22float2(*(__half2*)&h.h[1]);
            float2 h2 = __half22float2(*(__half2*)&h.h[2]);
            float2 h3 = __half22float2(*(__half2*)&h.h[3]);
            a0 = fmaf(w0.x, h0.x, a0); a1 = fmaf(w0.y, h0.y, a1);
            a2 = fmaf(w0.z, h1.x, a2); a3 = fmaf(w0.w, h1.y, a3);
            a0 = fmaf(w1.x, h2.x, a0); a1 = fmaf(w1.y, h2.y, a1);
            a2 = fmaf(w1.z, h3.x, a2); a3 = fmaf(w1.w, h3.y, a3);
        }
        hn = tanhf((a0 + a1) + (a2 + a3));
        outb[(size_t)t * (BATCH * HID)] = hn;
        hs[cur ^ 1][j] = __float2half(hn);
        __syncthreads();
        cur ^= 1;
    }
    out[(size_t)T_STEPS * BATCH * HID + (size_t)b * HID + j] = hn;
}

// ---------------------------------------------------------------------------
extern "C" void kernel_launch(void* const* d_in, const int* in_sizes, int n_in,
                              void* d_out, int out_size, void* d_ws, size_t ws_size,
                              hipStream_t stream) {
    const float* x    = (const float*)d_in[0];
    const float* w_ih = (const float*)d_in[1];
    const float* w_hh = (const float*)d_in[2];
    const float* b_ih = (const float*)d_in[3];
    const float* b_hh = (const float*)d_in[4];
    float* out = (float*)d_out;

    char* ws = (char*)d_ws;
    const bool full = ws_size >= (size_t)WS_FULL;
    const bool mid  = ws_size >= (size_t)WHH_BYTES;

    if (full) {
        __half*         xp16  = (__half*)(ws + XP16_OFF);
        unsigned short* wih16 = (unsigned short*)(ws + WIH_OFF);
        __half*         whh16 = (__half*)(ws + WHH_OFF);
        cvt_bf16<<<256, 256, 0, stream>>>(w_ih, wih16);
        cvt_f16 <<<256, 256, 0, stream>>>(w_hh, whh16);
        xproj_mfma<<<dim3(4, 256), 256, 0, stream>>>(x, wih16, b_ih, b_hh, xp16);
        rnn_scan6<<<4, 512, 0, stream>>>(whh16, xp16, out);
    } else if (mid) {
        __half* whh16 = (__half*)ws;
        cvt_f16<<<256, 256, 0, stream>>>(w_hh, whh16);
        xproj_gemm<<<dim3(8, 512), 256, 0, stream>>>(x, w_ih, b_ih, b_hh, out);
        rnn_scan4<<<BATCH, HID, 0, stream>>>(whh16, out);
    } else {
        xproj_gemm<<<dim3(8, 512), 256, 0, stream>>>(x, w_ih, b_ih, b_hh, out);
        rnn_scan_f32<<<BATCH, HID, 0, stream>>>(w_hh, out);
    }
}

// Round 4
// 1216.395 us; speedup vs baseline: 3.8084x; 1.1674x over previous
//
#include <hip/hip_runtime.h>
#include <hip/hip_fp16.h>

#define T_STEPS 512
#define BATCH   64
#define HID     512

// ---- scan7 geometry: grid=4 blocks x 16 batches, 8 waves x 64 rows ----
// W per wave = 64 rows x 512 k = 64 frags (16B/lane each).
//   tau0..2 (48 frags) -> VGPR (192 regs, needs the 256 budget!)
//   tau3    (16 frags) -> LDS  (8 waves x 16 KB = 128 KB)
#define NB      16

// ---- scan4 (fallback) W-row split ----
#define SCH_REG  40
#define SCH_LDS  10
#define SCH_SA   7
#define SCH_SB   7

// Workspace layout (unchanged, ~34.6 MB):
#define XP16_OFF  0u
#define XP16_BYTES (16777216u * 2u)         // 32 MB f16 xp (chunk layout)
#define WIH_OFF   (XP16_OFF + XP16_BYTES)
#define WIH_BYTES (262144u * 2u)
#define WHH_OFF   (WIH_OFF + WIH_BYTES)
#define WHH_BYTES (262144u * 2u)
#define WS_FULL   (WHH_OFF + WHH_BYTES)

typedef _Float16 half2v  __attribute__((ext_vector_type(2)));
typedef _Float16 half4v  __attribute__((ext_vector_type(4)));
typedef _Float16 half8   __attribute__((ext_vector_type(8)));
typedef short    short8  __attribute__((ext_vector_type(8)));
typedef float    f32x4   __attribute__((ext_vector_type(4)));
union F4H  { float4 f; half2v h[4]; };

__device__ inline float dot2f(half2v a, half2v b, float c) {
    return __builtin_amdgcn_fdot2(a, b, c, false);
}
__device__ inline unsigned short f2bf(float f) {
    unsigned u = __builtin_bit_cast(unsigned, f);
    return (unsigned short)((u + 0x7FFFu + ((u >> 16) & 1u)) >> 16);
}

// ---------------------------------------------------------------------------
// Conversions (re-run every call; ws is re-poisoned by the harness).
// ---------------------------------------------------------------------------
__global__ __launch_bounds__(256) void cvt_f16(const float* __restrict__ w,
                                               __half* __restrict__ o) {
    const int i = (blockIdx.x * 256 + threadIdx.x) * 4;
    float4 v = *(const float4*)(w + i);
    __half2 p0; p0.x = __float2half(v.x); p0.y = __float2half(v.y);
    __half2 p1; p1.x = __float2half(v.z); p1.y = __float2half(v.w);
    *(__half2*)(o + i)     = p0;
    *(__half2*)(o + i + 2) = p1;
}

__global__ __launch_bounds__(256) void cvt_bf16(const float* __restrict__ s,
                                                unsigned short* __restrict__ o) {
    const int i = (blockIdx.x * 256 + threadIdx.x) * 4;
    float4 v = *(const float4*)(s + i);
    ushort4 r = {f2bf(v.x), f2bf(v.y), f2bf(v.z), f2bf(v.w)};
    *(ushort4*)(o + i) = r;
}

// ---------------------------------------------------------------------------
// xproj via bf16 MFMA. Reads x f32 (converts in staging), writes f16 xp16
// in the scan's chunk layout:
//   half-index(t,b,o) = t*32768 + (b>>4)*8192 + (o>>3)*128 + (b&15)*8 + (o&7)
// ---------------------------------------------------------------------------
__global__ __launch_bounds__(256) void xproj_mfma(
    const float* __restrict__ x,
    const unsigned short* __restrict__ w16,
    const float* __restrict__ b_ih, const float* __restrict__ b_hh,
    __half* __restrict__ xp16)
{
    __shared__ __align__(16) unsigned short As[128][40];
    __shared__ __align__(16) unsigned short Bs[128][40];

    const int tid   = threadIdx.x;
    const int mBase = blockIdx.y * 128;
    const int nBase = blockIdx.x * 128;
    const int wave  = tid >> 6, lane = tid & 63;
    const int wy    = wave >> 1, wx = wave & 1;
    const int quad  = lane >> 4, l15 = lane & 15;
    const int lr    = tid >> 2;
    const int lk    = (tid & 3) * 8;

    f32x4 acc[4][4] = {};

    const size_t arow0 = (size_t)(mBase + lr) * 512 + lk;
    const size_t brow0 = (size_t)(nBase + lr) * 512 + lk;

    for (int k0 = 0; k0 < 512; k0 += 32) {
        float4 a0l = *(const float4*)(x + arow0 + k0);
        float4 a0h = *(const float4*)(x + arow0 + k0 + 4);
        float4 a1l = *(const float4*)(x + arow0 + (size_t)64 * 512 + k0);
        float4 a1h = *(const float4*)(x + arow0 + (size_t)64 * 512 + k0 + 4);
        int4 b0 = *(const int4*)(w16 + brow0 + k0);
        int4 b1 = *(const int4*)(w16 + brow0 + (size_t)64 * 512 + k0);
        int4 A0, A1;
        A0.x = f2bf(a0l.x) | ((unsigned)f2bf(a0l.y) << 16);
        A0.y = f2bf(a0l.z) | ((unsigned)f2bf(a0l.w) << 16);
        A0.z = f2bf(a0h.x) | ((unsigned)f2bf(a0h.y) << 16);
        A0.w = f2bf(a0h.z) | ((unsigned)f2bf(a0h.w) << 16);
        A1.x = f2bf(a1l.x) | ((unsigned)f2bf(a1l.y) << 16);
        A1.y = f2bf(a1l.z) | ((unsigned)f2bf(a1l.w) << 16);
        A1.z = f2bf(a1h.x) | ((unsigned)f2bf(a1h.y) << 16);
        A1.w = f2bf(a1h.z) | ((unsigned)f2bf(a1h.w) << 16);
        __syncthreads();
        *(int4*)&As[lr][lk]      = A0;
        *(int4*)&As[lr + 64][lk] = A1;
        *(int4*)&Bs[lr][lk]      = b0;
        *(int4*)&Bs[lr + 64][lk] = b1;
        __syncthreads();

        short8 af[4], bf[4];
#pragma unroll
        for (int mt = 0; mt < 4; ++mt)
            af[mt] = *(const short8*)&As[wy * 64 + mt * 16 + l15][quad * 8];
#pragma unroll
        for (int nt = 0; nt < 4; ++nt)
            bf[nt] = *(const short8*)&Bs[wx * 64 + nt * 16 + l15][quad * 8];
#pragma unroll
        for (int mt = 0; mt < 4; ++mt)
#pragma unroll
            for (int nt = 0; nt < 4; ++nt)
                acc[mt][nt] = __builtin_amdgcn_mfma_f32_16x16x32_bf16(
                    af[mt], bf[nt], acc[mt][nt], 0, 0, 0);
    }

    float bias[4]; int coln[4];
#pragma unroll
    for (int nt = 0; nt < 4; ++nt) {
        coln[nt] = nBase + wx * 64 + nt * 16 + l15;
        bias[nt] = b_ih[coln[nt]] + b_hh[coln[nt]];
    }
#pragma unroll
    for (int mt = 0; mt < 4; ++mt)
#pragma unroll
        for (int r = 0; r < 4; ++r) {
            const int m = mBase + wy * 64 + mt * 16 + quad * 4 + r;
            const int tt = m >> 6, b = m & 63;
#pragma unroll
            for (int nt = 0; nt < 4; ++nt) {
                const int o = coln[nt];
                const size_t idx = (size_t)tt * 32768 + (size_t)(b >> 4) * 8192
                                 + (o >> 3) * 128 + (b & 15) * 8 + (o & 7);
                xp16[idx] = __float2half(acc[mt][nt][r] + bias[nt]);
            }
        }
}

// ---------------------------------------------------------------------------
// Fallback fp32 xproj (writes f32 xproj into out, scan4-compatible).
// ---------------------------------------------------------------------------
__global__ __launch_bounds__(256) void xproj_gemm(
    const float* __restrict__ x, const float* __restrict__ w_ih,
    const float* __restrict__ b_ih, const float* __restrict__ b_hh,
    float* __restrict__ out)
{
    __shared__ __align__(16) float As[16][68];
    __shared__ __align__(16) float Bs[16][68];

    const int tid   = threadIdx.x;
    const int tx    = tid & 15;
    const int ty    = tid >> 4;
    const int mBase = blockIdx.y * 64;
    const int nBase = blockIdx.x * 64;
    const int ldr   = tid >> 2;
    const int ldk   = (tid & 3) * 4;

    float acc[4][4] = {};
    const float* aptr = x    + (size_t)(mBase + ldr) * 512 + ldk;
    const float* bptr = w_ih + (size_t)(nBase + ldr) * 512 + ldk;

    for (int k0 = 0; k0 < 512; k0 += 16) {
        float4 av = *(const float4*)(aptr + k0);
        float4 bv = *(const float4*)(bptr + k0);
        __syncthreads();
        As[ldk + 0][ldr] = av.x; As[ldk + 1][ldr] = av.y;
        As[ldk + 2][ldr] = av.z; As[ldk + 3][ldr] = av.w;
        Bs[ldk + 0][ldr] = bv.x; Bs[ldk + 1][ldr] = bv.y;
        Bs[ldk + 2][ldr] = bv.z; Bs[ldk + 3][ldr] = bv.w;
        __syncthreads();
#pragma unroll
        for (int kk = 0; kk < 16; ++kk) {
            float4 a = *(const float4*)&As[kk][ty * 4];
            float4 b = *(const float4*)&Bs[kk][tx * 4];
            float ar[4] = {a.x, a.y, a.z, a.w};
            float br[4] = {b.x, b.y, b.z, b.w};
#pragma unroll
            for (int i = 0; i < 4; ++i)
#pragma unroll
                for (int j = 0; j < 4; ++j)
                    acc[i][j] = fmaf(ar[i], br[j], acc[i][j]);
        }
    }
    const int n0 = nBase + tx * 4;
    float bias[4];
#pragma unroll
    for (int j = 0; j < 4; ++j) bias[j] = b_ih[n0 + j] + b_hh[n0 + j];
#pragma unroll
    for (int i = 0; i < 4; ++i) {
        const int m = mBase + ty * 4 + i;
        float4 v = {acc[i][0] + bias[0], acc[i][1] + bias[1],
                    acc[i][2] + bias[2], acc[i][3] + bias[3]};
        *(float4*)(out + (size_t)m * 512 + n0) = v;
    }
}

// ---------------------------------------------------------------------------
// Scan v7: MFMA scan, full W residency.
//   __launch_bounds__(512, 2): min 2 waves/EU -> 256-VGPR budget. This is
//   THE fix for R2/R3's VGPR_Count=128 (W was silently re-streamed from L2
//   every step). tau0..2 W in VGPR (192), tau3 W in LDS (128 KB), h in LDS
//   chunk layout (16 KB). Out written directly from registers (kills the
//   2.23M-conflict out-stage). 2 barriers/step, zero global W traffic.
// ---------------------------------------------------------------------------
#define PIN8(a) asm volatile("" : "+v"(a[0]), "+v"(a[1]), "+v"(a[2]), "+v"(a[3]), \
                                  "+v"(a[4]), "+v"(a[5]), "+v"(a[6]), "+v"(a[7]))

__global__ __launch_bounds__(512, 2)
void rnn_scan7(const __half* __restrict__ whh16,
               const __half* __restrict__ xp16,
               float* __restrict__ out)
{
    __shared__ __align__(16) _Float16 hlds[64 * NB * 8];          // 16 KB
    __shared__ __align__(16) _Float16 alds[8 * 16 * 512];         // 128 KB

    const int bg   = blockIdx.x;
    const int tid  = threadIdx.x;
    const int w    = tid >> 6;
    const int lane = tid & 63;
    const int q    = lane >> 4;
    const int l15  = lane & 15;

    // ---- W fragments: row = 64w + 16*tau + l15, k = 32*ki + 8q + j ----
    const __half* wbase = whh16 + ((size_t)(64 * w + l15)) * 512 + 8 * q;
    half8 wf0[16], wf1[16], wf2[16];
#pragma unroll
    for (int ki = 0; ki < 16; ++ki) {
        wf0[ki] = *(const half8*)(wbase + 32 * ki);
        wf1[ki] = *(const half8*)(wbase + (size_t)16 * 512 + 32 * ki);
        wf2[ki] = *(const half8*)(wbase + (size_t)32 * 512 + 32 * ki);
    }
    // tau3 -> LDS (per-wave, contiguous 1 KB per (w,ki): conflict-free b128)
#pragma unroll
    for (int ki = 0; ki < 16; ++ki) {
        half8 v = *(const half8*)(wbase + (size_t)48 * 512 + 32 * ki);
        *(half8*)&alds[(w * 16 + ki) * 512 + lane * 8] = v;
    }
    // zero h_0
    {
        float4 z = {0.f, 0.f, 0.f, 0.f};
        *(float4*)&hlds[tid * 16]     = z;
        *(float4*)&hlds[tid * 16 + 8] = z;
    }
    __syncthreads();

    // chunk-layout index for (o = 64w+16*tau+4q+r, batch=l15):
    //   idx = (8w+2*tau+(q>>1))*128 + l15*8 + (q&1)*4 + r    (halfs)
    int cidx[4];
#pragma unroll
    for (int ta = 0; ta < 4; ++ta)
        cidx[ta] = (8 * w + 2 * ta + (q >> 1)) * 128 + l15 * 8 + (q & 1) * 4;

    const __half* xpb = xp16 + (size_t)bg * 8192;   // + t*32768 + cidx[ta]

    // direct out store: batch = bg*16+l15, o = 64w + 16*ta + 4q + r
    float* outr = out + (size_t)(bg * 16 + l15) * 512 + 64 * w + 4 * q;
    const size_t ostride = (size_t)BATCH * HID;

    for (int t = 0; t < T_STEPS; ++t) {
        // xp for this step (consumed in phase B)
        uint2 xpv0 = *(const uint2*)(xpb + (size_t)t * 32768 + cidx[0]);
        uint2 xpv1 = *(const uint2*)(xpb + (size_t)t * 32768 + cidx[1]);
        uint2 xpv2 = *(const uint2*)(xpb + (size_t)t * 32768 + cidx[2]);
        uint2 xpv3 = *(const uint2*)(xpb + (size_t)t * 32768 + cidx[3]);

        // ---- phase A: 64 MFMA ----
        f32x4 acc0 = {0.f, 0.f, 0.f, 0.f};
        f32x4 acc1 = {0.f, 0.f, 0.f, 0.f};
        f32x4 acc2 = {0.f, 0.f, 0.f, 0.f};
        f32x4 acc3 = {0.f, 0.f, 0.f, 0.f};
#pragma unroll
        for (int ki = 0; ki < 16; ++ki) {
            half8 bfr = *(const half8*)&hlds[(4 * ki + q) * 128 + l15 * 8];
            half8 a3  = *(const half8*)&alds[(w * 16 + ki) * 512 + lane * 8];
            acc0 = __builtin_amdgcn_mfma_f32_16x16x32_f16(wf0[ki], bfr, acc0, 0, 0, 0);
            acc1 = __builtin_amdgcn_mfma_f32_16x16x32_f16(wf1[ki], bfr, acc1, 0, 0, 0);
            acc2 = __builtin_amdgcn_mfma_f32_16x16x32_f16(wf2[ki], bfr, acc2, 0, 0, 0);
            acc3 = __builtin_amdgcn_mfma_f32_16x16x32_f16(a3,      bfr, acc3, 0, 0, 0);
        }
        __syncthreads();   // barrier1: all reads of hlds(h_{t-1}) done

        // ---- phase B: xp add + tanh + h writeback + direct out store ----
#pragma unroll
        for (int ta = 0; ta < 4; ++ta) {
            const uint2 xv = (ta == 0) ? xpv0 : (ta == 1) ? xpv1
                           : (ta == 2) ? xpv2 : xpv3;
            const half4v xh = __builtin_bit_cast(half4v, xv);
            const f32x4 A = (ta == 0) ? acc0 : (ta == 1) ? acc1
                          : (ta == 2) ? acc2 : acc3;
            half4v hv;
            float4 ov;
#pragma unroll
            for (int r = 0; r < 4; ++r) {
                float s = A[r] + (float)xh[r];
                s = fminf(fmaxf(s, -15.f), 15.f);
                const float e = __expf(2.f * s);
                const float hnf = (e - 1.f) * __builtin_amdgcn_rcpf(e + 1.f);
                hv[r] = (_Float16)hnf;
                ov[r] = hnf;
            }
            *(half4v*)&hlds[cidx[ta]] = hv;
            *(float4*)(outr + (size_t)t * ostride + 16 * ta) = ov;
            if (t == T_STEPS - 1)
                *(float4*)(outr + (size_t)T_STEPS * ostride + 16 * ta) = ov;
        }
        // keep W fragments live-in-register across the loop (anti-remat)
        PIN8(wf0); PIN8((wf0 + 8));
        PIN8(wf1); PIN8((wf1 + 8));
        PIN8(wf2); PIN8((wf2 + 8));
        __syncthreads();   // barrier2: h_t visible for next step
    }
}

// ---------------------------------------------------------------------------
// Scan v4 (mid-workspace fallback; reads f32 xproj from out in-place).
// ---------------------------------------------------------------------------
#define ACC4(WF, G) do {                                        \
    F4H hh_; hh_.f = *(const float4*)(hrow + (G) * 8);          \
    F4H ww_; ww_.f = (WF);                                      \
    a0 = dot2f(ww_.h[0], hh_.h[0], a0);                         \
    a1 = dot2f(ww_.h[1], hh_.h[1], a1);                         \
    a2 = dot2f(ww_.h[2], hh_.h[2], a2);                         \
    a3 = dot2f(ww_.h[3], hh_.h[3], a3); } while (0)

__global__ __launch_bounds__(512, 2)
void rnn_scan4(const __half* __restrict__ w16, float* __restrict__ out)
{
    __shared__ __align__(16) float4 wlds[SCH_LDS][HID];
    __shared__ __align__(16) __half hbuf[2][HID];

    const int b = blockIdx.x;
    const int j = threadIdx.x;

    const __half* wrow = w16 + (size_t)j * HID;

    float4 wreg[SCH_REG];
#pragma unroll
    for (int c = 0; c < SCH_REG; ++c)
        wreg[c] = *(const float4*)(wrow + c * 8);

#pragma unroll
    for (int c = 0; c < SCH_LDS; ++c)
        wlds[c][j] = *(const float4*)(wrow + (SCH_REG + c) * 8);

    hbuf[0][j] = __float2half(0.f);
    __syncthreads();

    float* outb = out + (size_t)b * HID + j;
    const size_t stride = (size_t)BATCH * HID;
    const __half* wstr = wrow + (SCH_REG + SCH_LDS) * 8;

    int cur = 0;
    float hn = 0.f;
    float xp_next = outb[0];

    for (int t = 0; t < T_STEPS; ++t) {
        const float xp = xp_next;
        const int tn = (t + 1 < T_STEPS) ? (t + 1) : t;
        xp_next = outb[(size_t)tn * stride];

        const __half* hrow = hbuf[cur];

        float4 wa[SCH_SA];
#pragma unroll
        for (int c = 0; c < SCH_SA; ++c)
            wa[c] = *(const float4*)(wstr + c * 8);

        float a0 = xp, a1 = 0.f, a2 = 0.f, a3 = 0.f;

#pragma unroll
        for (int c = 0; c < 20; ++c) ACC4(wreg[c], c);
#pragma unroll
        for (int c = 0; c < SCH_SA; ++c)
            ACC4(wa[c], SCH_REG + SCH_LDS + c);

        float4 wb[SCH_SB];
#pragma unroll
        for (int c = 0; c < SCH_SB; ++c)
            wb[c] = *(const float4*)(wstr + (SCH_SA + c) * 8);

#pragma unroll
        for (int c = 20; c < SCH_REG; ++c) ACC4(wreg[c], c);
#pragma unroll
        for (int c = 0; c < SCH_LDS; ++c) {
            float4 wfv = wlds[c][j];
            ACC4(wfv, SCH_REG + c);
        }

#pragma unroll
        for (int c = 0; c < SCH_SB; ++c)
            ACC4(wb[c], SCH_REG + SCH_LDS + SCH_SA + c);

        float s = (a0 + a1) + (a2 + a3);
        s = fminf(fmaxf(s, -15.f), 15.f);
        const float e = __expf(2.f * s);
        hn = (e - 1.f) * __builtin_amdgcn_rcpf(e + 1.f);

        outb[(size_t)t * stride] = hn;
        hbuf[cur ^ 1][j] = __float2half(hn);
        __syncthreads();
        cur ^= 1;
    }
    out[(size_t)T_STEPS * stride + (size_t)b * HID + j] = hn;
}

// ---------------------------------------------------------------------------
// Last-resort fp32 scan (no workspace needed).
// ---------------------------------------------------------------------------
__global__ __launch_bounds__(512) void rnn_scan_f32(const float* __restrict__ w,
                                                    float* __restrict__ out)
{
    __shared__ __align__(16) __half hs[2][HID];
    const int b = blockIdx.x;
    const int j = threadIdx.x;

    hs[0][j] = __float2half(0.f);
    __syncthreads();

    const float* wrow32 = w + (size_t)j * HID;
    float* outb = out + (size_t)b * HID + j;
    int cur = 0;
    float hn = 0.f;

    for (int t = 0; t < T_STEPS; ++t) {
        float a0 = outb[(size_t)t * (BATCH * HID)];
        float a1 = 0.f, a2 = 0.f, a3 = 0.f;
#pragma unroll 4
        for (int k0 = 0; k0 < HID; k0 += 8) {
            float4 w0 = *(const float4*)(wrow32 + k0);
            float4 w1 = *(const float4*)(wrow32 + k0 + 4);
            F4H h; h.f = *(const float4*)(&hs[cur][k0]);
            float2 h0 = __half22float2(*(__half2*)&h.h[0]);
            float2 h1 = __half22float2(*(__half2*)&h.h[1]);
            float2 h2 = __half22float2(*(__half2*)&h.h[2]);
            float2 h3 = __half22float2(*(__half2*)&h.h[3]);
            a0 = fmaf(w0.x, h0.x, a0); a1 = fmaf(w0.y, h0.y, a1);
            a2 = fmaf(w0.z, h1.x, a2); a3 = fmaf(w0.w, h1.y, a3);
            a0 = fmaf(w1.x, h2.x, a0); a1 = fmaf(w1.y, h2.y, a1);
            a2 = fmaf(w1.z, h3.x, a2); a3 = fmaf(w1.w, h3.y, a3);
        }
        hn = tanhf((a0 + a1) + (a2 + a3));
        outb[(size_t)t * (BATCH * HID)] = hn;
        hs[cur ^ 1][j] = __float2half(hn);
        __syncthreads();
        cur ^= 1;
    }
    out[(size_t)T_STEPS * BATCH * HID + (size_t)b * HID + j] = hn;
}

// ---------------------------------------------------------------------------
extern "C" void kernel_launch(void* const* d_in, const int* in_sizes, int n_in,
                              void* d_out, int out_size, void* d_ws, size_t ws_size,
                              hipStream_t stream) {
    const float* x    = (const float*)d_in[0];
    const float* w_ih = (const float*)d_in[1];
    const float* w_hh = (const float*)d_in[2];
    const float* b_ih = (const float*)d_in[3];
    const float* b_hh = (const float*)d_in[4];
    float* out = (float*)d_out;

    char* ws = (char*)d_ws;
    const bool full = ws_size >= (size_t)WS_FULL;
    const bool mid  = ws_size >= (size_t)WHH_BYTES;

    if (full) {
        __half*         xp16  = (__half*)(ws + XP16_OFF);
        unsigned short* wih16 = (unsigned short*)(ws + WIH_OFF);
        __half*         whh16 = (__half*)(ws + WHH_OFF);
        cvt_bf16<<<256, 256, 0, stream>>>(w_ih, wih16);
        cvt_f16 <<<256, 256, 0, stream>>>(w_hh, whh16);
        xproj_mfma<<<dim3(4, 256), 256, 0, stream>>>(x, wih16, b_ih, b_hh, xp16);
        rnn_scan7<<<4, 512, 0, stream>>>(whh16, xp16, out);
    } else if (mid) {
        __half* whh16 = (__half*)ws;
        cvt_f16<<<256, 256, 0, stream>>>(w_hh, whh16);
        xproj_gemm<<<dim3(8, 512), 256, 0, stream>>>(x, w_ih, b_ih, b_hh, out);
        rnn_scan4<<<BATCH, HID, 0, stream>>>(whh16, out);
    } else {
        xproj_gemm<<<dim3(8, 512), 256, 0, stream>>>(x, w_ih, b_ih, b_hh, out);
        rnn_scan_f32<<<BATCH, HID, 0, stream>>>(w_hh, out);
    }
}

// Round 5
// 1213.737 us; speedup vs baseline: 3.8168x; 1.0022x over previous
//
#include <hip/hip_runtime.h>
#include <hip/hip_fp16.h>

#define T_STEPS 512
#define BATCH   64
#define HID     512

// ---- scan7 geometry: grid=4 blocks x 16 batches, 8 waves x 64 rows ----
// W per wave = 64 rows x 512 k = 64 frags (16B/lane each).
//   tau0..2 (48 frags) -> VGPR (192 regs; needs budget >> 256 -> waves_per_eu(1,2))
//   tau3    (16 frags) -> LDS  (8 waves x 16 KB = 128 KB)
#define NB      16

// ---- scan4 (fallback) W-row split ----
#define SCH_REG  40
#define SCH_LDS  10
#define SCH_SA   7
#define SCH_SB   7

// Workspace layout (unchanged, ~34.6 MB):
#define XP16_OFF  0u
#define XP16_BYTES (16777216u * 2u)         // 32 MB f16 xp (chunk layout)
#define WIH_OFF   (XP16_OFF + XP16_BYTES)
#define WIH_BYTES (262144u * 2u)
#define WHH_OFF   (WIH_OFF + WIH_BYTES)
#define WHH_BYTES (262144u * 2u)
#define WS_FULL   (WHH_OFF + WHH_BYTES)

typedef _Float16 half2v  __attribute__((ext_vector_type(2)));
typedef _Float16 half4v  __attribute__((ext_vector_type(4)));
typedef _Float16 half8   __attribute__((ext_vector_type(8)));
typedef short    short8  __attribute__((ext_vector_type(8)));
typedef float    f32x4   __attribute__((ext_vector_type(4)));
union F4H  { float4 f; half2v h[4]; };

__device__ inline float dot2f(half2v a, half2v b, float c) {
    return __builtin_amdgcn_fdot2(a, b, c, false);
}
__device__ inline unsigned short f2bf(float f) {
    unsigned u = __builtin_bit_cast(unsigned, f);
    return (unsigned short)((u + 0x7FFFu + ((u >> 16) & 1u)) >> 16);
}

// ---------------------------------------------------------------------------
// Conversions (re-run every call; ws is re-poisoned by the harness).
// ---------------------------------------------------------------------------
__global__ __launch_bounds__(256) void cvt_f16(const float* __restrict__ w,
                                               __half* __restrict__ o) {
    const int i = (blockIdx.x * 256 + threadIdx.x) * 4;
    float4 v = *(const float4*)(w + i);
    __half2 p0; p0.x = __float2half(v.x); p0.y = __float2half(v.y);
    __half2 p1; p1.x = __float2half(v.z); p1.y = __float2half(v.w);
    *(__half2*)(o + i)     = p0;
    *(__half2*)(o + i + 2) = p1;
}

__global__ __launch_bounds__(256) void cvt_bf16(const float* __restrict__ s,
                                                unsigned short* __restrict__ o) {
    const int i = (blockIdx.x * 256 + threadIdx.x) * 4;
    float4 v = *(const float4*)(s + i);
    ushort4 r = {f2bf(v.x), f2bf(v.y), f2bf(v.z), f2bf(v.w)};
    *(ushort4*)(o + i) = r;
}

// ---------------------------------------------------------------------------
// xproj via bf16 MFMA. Reads x f32 (converts in staging), writes f16 xp16
// in the scan's chunk layout:
//   half-index(t,b,o) = t*32768 + (b>>4)*8192 + (o>>3)*128 + (b&15)*8 + (o&7)
// ---------------------------------------------------------------------------
__global__ __launch_bounds__(256) void xproj_mfma(
    const float* __restrict__ x,
    const unsigned short* __restrict__ w16,
    const float* __restrict__ b_ih, const float* __restrict__ b_hh,
    __half* __restrict__ xp16)
{
    __shared__ __align__(16) unsigned short As[128][40];
    __shared__ __align__(16) unsigned short Bs[128][40];

    const int tid   = threadIdx.x;
    const int mBase = blockIdx.y * 128;
    const int nBase = blockIdx.x * 128;
    const int wave  = tid >> 6, lane = tid & 63;
    const int wy    = wave >> 1, wx = wave & 1;
    const int quad  = lane >> 4, l15 = lane & 15;
    const int lr    = tid >> 2;
    const int lk    = (tid & 3) * 8;

    f32x4 acc[4][4] = {};

    const size_t arow0 = (size_t)(mBase + lr) * 512 + lk;
    const size_t brow0 = (size_t)(nBase + lr) * 512 + lk;

    for (int k0 = 0; k0 < 512; k0 += 32) {
        float4 a0l = *(const float4*)(x + arow0 + k0);
        float4 a0h = *(const float4*)(x + arow0 + k0 + 4);
        float4 a1l = *(const float4*)(x + arow0 + (size_t)64 * 512 + k0);
        float4 a1h = *(const float4*)(x + arow0 + (size_t)64 * 512 + k0 + 4);
        int4 b0 = *(const int4*)(w16 + brow0 + k0);
        int4 b1 = *(const int4*)(w16 + brow0 + (size_t)64 * 512 + k0);
        int4 A0, A1;
        A0.x = f2bf(a0l.x) | ((unsigned)f2bf(a0l.y) << 16);
        A0.y = f2bf(a0l.z) | ((unsigned)f2bf(a0l.w) << 16);
        A0.z = f2bf(a0h.x) | ((unsigned)f2bf(a0h.y) << 16);
        A0.w = f2bf(a0h.z) | ((unsigned)f2bf(a0h.w) << 16);
        A1.x = f2bf(a1l.x) | ((unsigned)f2bf(a1l.y) << 16);
        A1.y = f2bf(a1l.z) | ((unsigned)f2bf(a1l.w) << 16);
        A1.z = f2bf(a1h.x) | ((unsigned)f2bf(a1h.y) << 16);
        A1.w = f2bf(a1h.z) | ((unsigned)f2bf(a1h.w) << 16);
        __syncthreads();
        *(int4*)&As[lr][lk]      = A0;
        *(int4*)&As[lr + 64][lk] = A1;
        *(int4*)&Bs[lr][lk]      = b0;
        *(int4*)&Bs[lr + 64][lk] = b1;
        __syncthreads();

        short8 af[4], bf[4];
#pragma unroll
        for (int mt = 0; mt < 4; ++mt)
            af[mt] = *(const short8*)&As[wy * 64 + mt * 16 + l15][quad * 8];
#pragma unroll
        for (int nt = 0; nt < 4; ++nt)
            bf[nt] = *(const short8*)&Bs[wx * 64 + nt * 16 + l15][quad * 8];
#pragma unroll
        for (int mt = 0; mt < 4; ++mt)
#pragma unroll
            for (int nt = 0; nt < 4; ++nt)
                acc[mt][nt] = __builtin_amdgcn_mfma_f32_16x16x32_bf16(
                    af[mt], bf[nt], acc[mt][nt], 0, 0, 0);
    }

    float bias[4]; int coln[4];
#pragma unroll
    for (int nt = 0; nt < 4; ++nt) {
        coln[nt] = nBase + wx * 64 + nt * 16 + l15;
        bias[nt] = b_ih[coln[nt]] + b_hh[coln[nt]];
    }
#pragma unroll
    for (int mt = 0; mt < 4; ++mt)
#pragma unroll
        for (int r = 0; r < 4; ++r) {
            const int m = mBase + wy * 64 + mt * 16 + quad * 4 + r;
            const int tt = m >> 6, b = m & 63;
#pragma unroll
            for (int nt = 0; nt < 4; ++nt) {
                const int o = coln[nt];
                const size_t idx = (size_t)tt * 32768 + (size_t)(b >> 4) * 8192
                                 + (o >> 3) * 128 + (b & 15) * 8 + (o & 7);
                xp16[idx] = __float2half(acc[mt][nt][r] + bias[nt]);
            }
        }
}

// ---------------------------------------------------------------------------
// Fallback fp32 xproj (writes f32 xproj into out, scan4-compatible).
// ---------------------------------------------------------------------------
__global__ __launch_bounds__(256) void xproj_gemm(
    const float* __restrict__ x, const float* __restrict__ w_ih,
    const float* __restrict__ b_ih, const float* __restrict__ b_hh,
    float* __restrict__ out)
{
    __shared__ __align__(16) float As[16][68];
    __shared__ __align__(16) float Bs[16][68];

    const int tid   = threadIdx.x;
    const int tx    = tid & 15;
    const int ty    = tid >> 4;
    const int mBase = blockIdx.y * 64;
    const int nBase = blockIdx.x * 64;
    const int ldr   = tid >> 2;
    const int ldk   = (tid & 3) * 4;

    float acc[4][4] = {};
    const float* aptr = x    + (size_t)(mBase + ldr) * 512 + ldk;
    const float* bptr = w_ih + (size_t)(nBase + ldr) * 512 + ldk;

    for (int k0 = 0; k0 < 512; k0 += 16) {
        float4 av = *(const float4*)(aptr + k0);
        float4 bv = *(const float4*)(bptr + k0);
        __syncthreads();
        As[ldk + 0][ldr] = av.x; As[ldk + 1][ldr] = av.y;
        As[ldk + 2][ldr] = av.z; As[ldk + 3][ldr] = av.w;
        Bs[ldk + 0][ldr] = bv.x; Bs[ldk + 1][ldr] = bv.y;
        Bs[ldk + 2][ldr] = bv.z; Bs[ldk + 3][ldr] = bv.w;
        __syncthreads();
#pragma unroll
        for (int kk = 0; kk < 16; ++kk) {
            float4 a = *(const float4*)&As[kk][ty * 4];
            float4 b = *(const float4*)&Bs[kk][tx * 4];
            float ar[4] = {a.x, a.y, a.z, a.w};
            float br[4] = {b.x, b.y, b.z, b.w};
#pragma unroll
            for (int i = 0; i < 4; ++i)
#pragma unroll
                for (int j = 0; j < 4; ++j)
                    acc[i][j] = fmaf(ar[i], br[j], acc[i][j]);
        }
    }
    const int n0 = nBase + tx * 4;
    float bias[4];
#pragma unroll
    for (int j = 0; j < 4; ++j) bias[j] = b_ih[n0 + j] + b_hh[n0 + j];
#pragma unroll
    for (int i = 0; i < 4; ++i) {
        const int m = mBase + ty * 4 + i;
        float4 v = {acc[i][0] + bias[0], acc[i][1] + bias[1],
                    acc[i][2] + bias[2], acc[i][3] + bias[3]};
        *(float4*)(out + (size_t)m * 512 + n0) = v;
    }
}

// ---------------------------------------------------------------------------
// Scan v7b: MFMA scan, full W residency — REGISTER-BUDGET FIX.
//   R4 post-mortem: __launch_bounds__(512,2) caps the budget at 256 while
//   demand is ~250; LLVM preemptively spilled the W frags (VGPR_Count=124)
//   and re-streamed 384 KB/step from L2 (~5000 cyc/step, the whole cost).
//   Fix: NO launch_bounds; amdgpu_flat_work_group_size(512,512) +
//   amdgpu_waves_per_eu(1,2) -> register ceiling 512/wave, occupancy target
//   2 waves/SIMD (LDS pins us there anyway). Demand 250 << 512 -> resident.
//   Diagnostic: VGPR_Count must jump to ~230+.
// ---------------------------------------------------------------------------
#define PIN8(a) asm volatile("" : "+v"(a[0]), "+v"(a[1]), "+v"(a[2]), "+v"(a[3]), \
                                  "+v"(a[4]), "+v"(a[5]), "+v"(a[6]), "+v"(a[7]))

__global__
__attribute__((amdgpu_flat_work_group_size(512, 512)))
__attribute__((amdgpu_waves_per_eu(1, 2)))
void rnn_scan7(const __half* __restrict__ whh16,
               const __half* __restrict__ xp16,
               float* __restrict__ out)
{
    __shared__ __align__(16) _Float16 hlds[64 * NB * 8];          // 16 KB
    __shared__ __align__(16) _Float16 alds[8 * 16 * 512];         // 128 KB

    const int bg   = blockIdx.x;
    const int tid  = threadIdx.x;
    const int w    = tid >> 6;
    const int lane = tid & 63;
    const int q    = lane >> 4;
    const int l15  = lane & 15;

    // ---- W fragments: row = 64w + 16*tau + l15, k = 32*ki + 8q + j ----
    const __half* wbase = whh16 + ((size_t)(64 * w + l15)) * 512 + 8 * q;
    half8 wf0[16], wf1[16], wf2[16];
#pragma unroll
    for (int ki = 0; ki < 16; ++ki) {
        wf0[ki] = *(const half8*)(wbase + 32 * ki);
        wf1[ki] = *(const half8*)(wbase + (size_t)16 * 512 + 32 * ki);
        wf2[ki] = *(const half8*)(wbase + (size_t)32 * 512 + 32 * ki);
    }
    // tau3 -> LDS (per-wave, contiguous 1 KB per (w,ki): conflict-free b128)
#pragma unroll
    for (int ki = 0; ki < 16; ++ki) {
        half8 v = *(const half8*)(wbase + (size_t)48 * 512 + 32 * ki);
        *(half8*)&alds[(w * 16 + ki) * 512 + lane * 8] = v;
    }
    // zero h_0
    {
        float4 z = {0.f, 0.f, 0.f, 0.f};
        *(float4*)&hlds[tid * 16]     = z;
        *(float4*)&hlds[tid * 16 + 8] = z;
    }
    __syncthreads();

    // chunk-layout index for (o = 64w+16*tau+4q+r, batch=l15):
    //   idx = (8w+2*tau+(q>>1))*128 + l15*8 + (q&1)*4 + r    (halfs)
    int cidx[4];
#pragma unroll
    for (int ta = 0; ta < 4; ++ta)
        cidx[ta] = (8 * w + 2 * ta + (q >> 1)) * 128 + l15 * 8 + (q & 1) * 4;

    const __half* xpb = xp16 + (size_t)bg * 8192;   // + t*32768 + cidx[ta]

    // direct out store: batch = bg*16+l15, o = 64w + 16*ta + 4q + r
    float* outr = out + (size_t)(bg * 16 + l15) * 512 + 64 * w + 4 * q;
    const size_t ostride = (size_t)BATCH * HID;

    for (int t = 0; t < T_STEPS; ++t) {
        // xp for this step (consumed in phase B; lives through phase A)
        uint2 xpv0 = *(const uint2*)(xpb + (size_t)t * 32768 + cidx[0]);
        uint2 xpv1 = *(const uint2*)(xpb + (size_t)t * 32768 + cidx[1]);
        uint2 xpv2 = *(const uint2*)(xpb + (size_t)t * 32768 + cidx[2]);
        uint2 xpv3 = *(const uint2*)(xpb + (size_t)t * 32768 + cidx[3]);

        // ---- phase A: 64 MFMA ----
        f32x4 acc0 = {0.f, 0.f, 0.f, 0.f};
        f32x4 acc1 = {0.f, 0.f, 0.f, 0.f};
        f32x4 acc2 = {0.f, 0.f, 0.f, 0.f};
        f32x4 acc3 = {0.f, 0.f, 0.f, 0.f};
#pragma unroll
        for (int ki = 0; ki < 16; ++ki) {
            half8 bfr = *(const half8*)&hlds[(4 * ki + q) * 128 + l15 * 8];
            half8 a3  = *(const half8*)&alds[(w * 16 + ki) * 512 + lane * 8];
            acc0 = __builtin_amdgcn_mfma_f32_16x16x32_f16(wf0[ki], bfr, acc0, 0, 0, 0);
            acc1 = __builtin_amdgcn_mfma_f32_16x16x32_f16(wf1[ki], bfr, acc1, 0, 0, 0);
            acc2 = __builtin_amdgcn_mfma_f32_16x16x32_f16(wf2[ki], bfr, acc2, 0, 0, 0);
            acc3 = __builtin_amdgcn_mfma_f32_16x16x32_f16(a3,      bfr, acc3, 0, 0, 0);
        }
        __syncthreads();   // barrier1: all reads of hlds(h_{t-1}) done

        // ---- phase B: xp add + tanh + h writeback + direct out store ----
#pragma unroll
        for (int ta = 0; ta < 4; ++ta) {
            const uint2 xv = (ta == 0) ? xpv0 : (ta == 1) ? xpv1
                           : (ta == 2) ? xpv2 : xpv3;
            const half4v xh = __builtin_bit_cast(half4v, xv);
            const f32x4 A = (ta == 0) ? acc0 : (ta == 1) ? acc1
                          : (ta == 2) ? acc2 : acc3;
            half4v hv;
            float4 ov;
#pragma unroll
            for (int r = 0; r < 4; ++r) {
                float s = A[r] + (float)xh[r];
                s = fminf(fmaxf(s, -15.f), 15.f);
                const float e = __expf(2.f * s);
                const float hnf = (e - 1.f) * __builtin_amdgcn_rcpf(e + 1.f);
                hv[r] = (_Float16)hnf;
                ov[r] = hnf;
            }
            *(half4v*)&hlds[cidx[ta]] = hv;
            *(float4*)(outr + (size_t)t * ostride + 16 * ta) = ov;
            if (t == T_STEPS - 1)
                *(float4*)(outr + (size_t)T_STEPS * ostride + 16 * ta) = ov;
        }
        // keep W fragments live-in-register across the loop (anti-remat)
        PIN8(wf0); PIN8((wf0 + 8));
        PIN8(wf1); PIN8((wf1 + 8));
        PIN8(wf2); PIN8((wf2 + 8));
        __syncthreads();   // barrier2: h_t visible for next step
    }
}

// ---------------------------------------------------------------------------
// Scan v4 (mid-workspace fallback; reads f32 xproj from out in-place).
// ---------------------------------------------------------------------------
#define ACC4(WF, G) do {                                        \
    F4H hh_; hh_.f = *(const float4*)(hrow + (G) * 8);          \
    F4H ww_; ww_.f = (WF);                                      \
    a0 = dot2f(ww_.h[0], hh_.h[0], a0);                         \
    a1 = dot2f(ww_.h[1], hh_.h[1], a1);                         \
    a2 = dot2f(ww_.h[2], hh_.h[2], a2);                         \
    a3 = dot2f(ww_.h[3], hh_.h[3], a3); } while (0)

__global__ __launch_bounds__(512, 2)
void rnn_scan4(const __half* __restrict__ w16, float* __restrict__ out)
{
    __shared__ __align__(16) float4 wlds[SCH_LDS][HID];
    __shared__ __align__(16) __half hbuf[2][HID];

    const int b = blockIdx.x;
    const int j = threadIdx.x;

    const __half* wrow = w16 + (size_t)j * HID;

    float4 wreg[SCH_REG];
#pragma unroll
    for (int c = 0; c < SCH_REG; ++c)
        wreg[c] = *(const float4*)(wrow + c * 8);

#pragma unroll
    for (int c = 0; c < SCH_LDS; ++c)
        wlds[c][j] = *(const float4*)(wrow + (SCH_REG + c) * 8);

    hbuf[0][j] = __float2half(0.f);
    __syncthreads();

    float* outb = out + (size_t)b * HID + j;
    const size_t stride = (size_t)BATCH * HID;
    const __half* wstr = wrow + (SCH_REG + SCH_LDS) * 8;

    int cur = 0;
    float hn = 0.f;
    float xp_next = outb[0];

    for (int t = 0; t < T_STEPS; ++t) {
        const float xp = xp_next;
        const int tn = (t + 1 < T_STEPS) ? (t + 1) : t;
        xp_next = outb[(size_t)tn * stride];

        const __half* hrow = hbuf[cur];

        float4 wa[SCH_SA];
#pragma unroll
        for (int c = 0; c < SCH_SA; ++c)
            wa[c] = *(const float4*)(wstr + c * 8);

        float a0 = xp, a1 = 0.f, a2 = 0.f, a3 = 0.f;

#pragma unroll
        for (int c = 0; c < 20; ++c) ACC4(wreg[c], c);
#pragma unroll
        for (int c = 0; c < SCH_SA; ++c)
            ACC4(wa[c], SCH_REG + SCH_LDS + c);

        float4 wb[SCH_SB];
#pragma unroll
        for (int c = 0; c < SCH_SB; ++c)
            wb[c] = *(const float4*)(wstr + (SCH_SA + c) * 8);

#pragma unroll
        for (int c = 20; c < SCH_REG; ++c) ACC4(wreg[c], c);
#pragma unroll
        for (int c = 0; c < SCH_LDS; ++c) {
            float4 wfv = wlds[c][j];
            ACC4(wfv, SCH_REG + c);
        }

#pragma unroll
        for (int c = 0; c < SCH_SB; ++c)
            ACC4(wb[c], SCH_REG + SCH_LDS + SCH_SA + c);

        float s = (a0 + a1) + (a2 + a3);
        s = fminf(fmaxf(s, -15.f), 15.f);
        const float e = __expf(2.f * s);
        hn = (e - 1.f) * __builtin_amdgcn_rcpf(e + 1.f);

        outb[(size_t)t * stride] = hn;
        hbuf[cur ^ 1][j] = __float2half(hn);
        __syncthreads();
        cur ^= 1;
    }
    out[(size_t)T_STEPS * stride + (size_t)b * HID + j] = hn;
}

// ---------------------------------------------------------------------------
// Last-resort fp32 scan (no workspace needed).
// ---------------------------------------------------------------------------
__global__ __launch_bounds__(512) void rnn_scan_f32(const float* __restrict__ w,
                                                    float* __restrict__ out)
{
    __shared__ __align__(16) __half hs[2][HID];
    const int b = blockIdx.x;
    const int j = threadIdx.x;

    hs[0][j] = __float2half(0.f);
    __syncthreads();

    const float* wrow32 = w + (size_t)j * HID;
    float* outb = out + (size_t)b * HID + j;
    int cur = 0;
    float hn = 0.f;

    for (int t = 0; t < T_STEPS; ++t) {
        float a0 = outb[(size_t)t * (BATCH * HID)];
        float a1 = 0.f, a2 = 0.f, a3 = 0.f;
#pragma unroll 4
        for (int k0 = 0; k0 < HID; k0 += 8) {
            float4 w0 = *(const float4*)(wrow32 + k0);
            float4 w1 = *(const float4*)(wrow32 + k0 + 4);
            F4H h; h.f = *(const float4*)(&hs[cur][k0]);
            float2 h0 = __half22float2(*(__half2*)&h.h[0]);
            float2 h1 = __half22float2(*(__half2*)&h.h[1]);
            float2 h2 = __half22float2(*(__half2*)&h.h[2]);
            float2 h3 = __half22float2(*(__half2*)&h.h[3]);
            a0 = fmaf(w0.x, h0.x, a0); a1 = fmaf(w0.y, h0.y, a1);
            a2 = fmaf(w0.z, h1.x, a2); a3 = fmaf(w0.w, h1.y, a3);
            a0 = fmaf(w1.x, h2.x, a0); a1 = fmaf(w1.y, h2.y, a1);
            a2 = fmaf(w1.z, h3.x, a2); a3 = fmaf(w1.w, h3.y, a3);
        }
        hn = tanhf((a0 + a1) + (a2 + a3));
        outb[(size_t)t * (BATCH * HID)] = hn;
        hs[cur ^ 1][j] = __float2half(hn);
        __syncthreads();
        cur ^= 1;
    }
    out[(size_t)T_STEPS * BATCH * HID + (size_t)b * HID + j] = hn;
}

// ---------------------------------------------------------------------------
extern "C" void kernel_launch(void* const* d_in, const int* in_sizes, int n_in,
                              void* d_out, int out_size, void* d_ws, size_t ws_size,
                              hipStream_t stream) {
    const float* x    = (const float*)d_in[0];
    const float* w_ih = (const float*)d_in[1];
    const float* w_hh = (const float*)d_in[2];
    const float* b_ih = (const float*)d_in[3];
    const float* b_hh = (const float*)d_in[4];
    float* out = (float*)d_out;

    char* ws = (char*)d_ws;
    const bool full = ws_size >= (size_t)WS_FULL;
    const bool mid  = ws_size >= (size_t)WHH_BYTES;

    if (full) {
        __half*         xp16  = (__half*)(ws + XP16_OFF);
        unsigned short* wih16 = (unsigned short*)(ws + WIH_OFF);
        __half*         whh16 = (__half*)(ws + WHH_OFF);
        cvt_bf16<<<256, 256, 0, stream>>>(w_ih, wih16);
        cvt_f16 <<<256, 256, 0, stream>>>(w_hh, whh16);
        xproj_mfma<<<dim3(4, 256), 256, 0, stream>>>(x, wih16, b_ih, b_hh, xp16);
        rnn_scan7<<<4, 512, 0, stream>>>(whh16, xp16, out);
    } else if (mid) {
        __half* whh16 = (__half*)ws;
        cvt_f16<<<256, 256, 0, stream>>>(w_hh, whh16);
        xproj_gemm<<<dim3(8, 512), 256, 0, stream>>>(x, w_ih, b_ih, b_hh, out);
        rnn_scan4<<<BATCH, HID, 0, stream>>>(whh16, out);
    } else {
        xproj_gemm<<<dim3(8, 512), 256, 0, stream>>>(x, w_ih, b_ih, b_hh, out);
        rnn_scan_f32<<<BATCH, HID, 0, stream>>>(w_hh, out);
    }
}

// Round 7
// 1198.356 us; speedup vs baseline: 3.8658x; 1.0128x over previous
//
#include <hip/hip_runtime.h>
#include <hip/hip_fp16.h>

#define T_STEPS 512
#define BATCH   64
#define HID     512

// ---- scan9 geometry: grid=4 blocks x 16 batches, 8 waves x 64 rows ----
// W per wave = 64 frags x 16B/lane:
//   tau0..2 (48 frags) -> AGPR via "=a" asm pin (192 acc regs; load-remat
//                         impossible: defining instr is the asm, not a load)
//   tau3    (16 frags) -> LDS (8 waves x 16 KB = 128 KB)
#define NB      16

// ---- scan4 (fallback) W-row split ----
#define SCH_REG  40
#define SCH_LDS  10
#define SCH_SA   7
#define SCH_SB   7

// Workspace layout (unchanged, ~34.6 MB):
#define XP16_OFF  0u
#define XP16_BYTES (16777216u * 2u)         // 32 MB f16 xp (chunk layout)
#define WIH_OFF   (XP16_OFF + XP16_BYTES)
#define WIH_BYTES (262144u * 2u)
#define WHH_OFF   (WIH_OFF + WIH_BYTES)
#define WHH_BYTES (262144u * 2u)
#define WS_FULL   (WHH_OFF + WHH_BYTES)

typedef _Float16 half2v  __attribute__((ext_vector_type(2)));
typedef _Float16 half4v  __attribute__((ext_vector_type(4)));
typedef _Float16 half8   __attribute__((ext_vector_type(8)));
typedef short    short8  __attribute__((ext_vector_type(8)));
typedef float    f32x4   __attribute__((ext_vector_type(4)));
union F4H  { float4 f; half2v h[4]; };

__device__ inline float dot2f(half2v a, half2v b, float c) {
    return __builtin_amdgcn_fdot2(a, b, c, false);
}
__device__ inline unsigned short f2bf(float f) {
    unsigned u = __builtin_bit_cast(unsigned, f);
    return (unsigned short)((u + 0x7FFFu + ((u >> 16) & 1u)) >> 16);
}

// ---------------------------------------------------------------------------
// Conversions (re-run every call; ws is re-poisoned by the harness).
// ---------------------------------------------------------------------------
__global__ __launch_bounds__(256) void cvt_f16(const float* __restrict__ w,
                                               __half* __restrict__ o) {
    const int i = (blockIdx.x * 256 + threadIdx.x) * 4;
    float4 v = *(const float4*)(w + i);
    __half2 p0; p0.x = __float2half(v.x); p0.y = __float2half(v.y);
    __half2 p1; p1.x = __float2half(v.z); p1.y = __float2half(v.w);
    *(__half2*)(o + i)     = p0;
    *(__half2*)(o + i + 2) = p1;
}

__global__ __launch_bounds__(256) void cvt_bf16(const float* __restrict__ s,
                                                unsigned short* __restrict__ o) {
    const int i = (blockIdx.x * 256 + threadIdx.x) * 4;
    float4 v = *(const float4*)(s + i);
    ushort4 r = {f2bf(v.x), f2bf(v.y), f2bf(v.z), f2bf(v.w)};
    *(ushort4*)(o + i) = r;
}

// ---------------------------------------------------------------------------
// xproj via bf16 MFMA. Reads x f32 (converts in staging), writes f16 xp16
// in the scan's chunk layout:
//   half-index(t,b,o) = t*32768 + (b>>4)*8192 + (o>>3)*128 + (b&15)*8 + (o&7)
// ---------------------------------------------------------------------------
__global__ __launch_bounds__(256) void xproj_mfma(
    const float* __restrict__ x,
    const unsigned short* __restrict__ w16,
    const float* __restrict__ b_ih, const float* __restrict__ b_hh,
    __half* __restrict__ xp16)
{
    __shared__ __align__(16) unsigned short As[128][40];
    __shared__ __align__(16) unsigned short Bs[128][40];

    const int tid   = threadIdx.x;
    const int mBase = blockIdx.y * 128;
    const int nBase = blockIdx.x * 128;
    const int wave  = tid >> 6, lane = tid & 63;
    const int wy    = wave >> 1, wx = wave & 1;
    const int quad  = lane >> 4, l15 = lane & 15;
    const int lr    = tid >> 2;
    const int lk    = (tid & 3) * 8;

    f32x4 acc[4][4] = {};

    const size_t arow0 = (size_t)(mBase + lr) * 512 + lk;
    const size_t brow0 = (size_t)(nBase + lr) * 512 + lk;

    for (int k0 = 0; k0 < 512; k0 += 32) {
        float4 a0l = *(const float4*)(x + arow0 + k0);
        float4 a0h = *(const float4*)(x + arow0 + k0 + 4);
        float4 a1l = *(const float4*)(x + arow0 + (size_t)64 * 512 + k0);
        float4 a1h = *(const float4*)(x + arow0 + (size_t)64 * 512 + k0 + 4);
        int4 b0 = *(const int4*)(w16 + brow0 + k0);
        int4 b1 = *(const int4*)(w16 + brow0 + (size_t)64 * 512 + k0);
        int4 A0, A1;
        A0.x = f2bf(a0l.x) | ((unsigned)f2bf(a0l.y) << 16);
        A0.y = f2bf(a0l.z) | ((unsigned)f2bf(a0l.w) << 16);
        A0.z = f2bf(a0h.x) | ((unsigned)f2bf(a0h.y) << 16);
        A0.w = f2bf(a0h.z) | ((unsigned)f2bf(a0h.w) << 16);
        A1.x = f2bf(a1l.x) | ((unsigned)f2bf(a1l.y) << 16);
        A1.y = f2bf(a1l.z) | ((unsigned)f2bf(a1l.w) << 16);
        A1.z = f2bf(a1h.x) | ((unsigned)f2bf(a1h.y) << 16);
        A1.w = f2bf(a1h.z) | ((unsigned)f2bf(a1h.w) << 16);
        __syncthreads();
        *(int4*)&As[lr][lk]      = A0;
        *(int4*)&As[lr + 64][lk] = A1;
        *(int4*)&Bs[lr][lk]      = b0;
        *(int4*)&Bs[lr + 64][lk] = b1;
        __syncthreads();

        short8 af[4], bf[4];
#pragma unroll
        for (int mt = 0; mt < 4; ++mt)
            af[mt] = *(const short8*)&As[wy * 64 + mt * 16 + l15][quad * 8];
#pragma unroll
        for (int nt = 0; nt < 4; ++nt)
            bf[nt] = *(const short8*)&Bs[wx * 64 + nt * 16 + l15][quad * 8];
#pragma unroll
        for (int mt = 0; mt < 4; ++mt)
#pragma unroll
            for (int nt = 0; nt < 4; ++nt)
                acc[mt][nt] = __builtin_amdgcn_mfma_f32_16x16x32_bf16(
                    af[mt], bf[nt], acc[mt][nt], 0, 0, 0);
    }

    float bias[4]; int coln[4];
#pragma unroll
    for (int nt = 0; nt < 4; ++nt) {
        coln[nt] = nBase + wx * 64 + nt * 16 + l15;
        bias[nt] = b_ih[coln[nt]] + b_hh[coln[nt]];
    }
#pragma unroll
    for (int mt = 0; mt < 4; ++mt)
#pragma unroll
        for (int r = 0; r < 4; ++r) {
            const int m = mBase + wy * 64 + mt * 16 + quad * 4 + r;
            const int tt = m >> 6, b = m & 63;
#pragma unroll
            for (int nt = 0; nt < 4; ++nt) {
                const int o = coln[nt];
                const size_t idx = (size_t)tt * 32768 + (size_t)(b >> 4) * 8192
                                 + (o >> 3) * 128 + (b & 15) * 8 + (o & 7);
                xp16[idx] = __float2half(acc[mt][nt][r] + bias[nt]);
            }
        }
}

// ---------------------------------------------------------------------------
// Fallback fp32 xproj (writes f32 xproj into out, scan4-compatible).
// ---------------------------------------------------------------------------
__global__ __launch_bounds__(256) void xproj_gemm(
    const float* __restrict__ x, const float* __restrict__ w_ih,
    const float* __restrict__ b_ih, const float* __restrict__ b_hh,
    float* __restrict__ out)
{
    __shared__ __align__(16) float As[16][68];
    __shared__ __align__(16) float Bs[16][68];

    const int tid   = threadIdx.x;
    const int tx    = tid & 15;
    const int ty    = tid >> 4;
    const int mBase = blockIdx.y * 64;
    const int nBase = blockIdx.x * 64;
    const int ldr   = tid >> 2;
    const int ldk   = (tid & 3) * 4;

    float acc[4][4] = {};
    const float* aptr = x    + (size_t)(mBase + ldr) * 512 + ldk;
    const float* bptr = w_ih + (size_t)(nBase + ldr) * 512 + ldk;

    for (int k0 = 0; k0 < 512; k0 += 16) {
        float4 av = *(const float4*)(aptr + k0);
        float4 bv = *(const float4*)(bptr + k0);
        __syncthreads();
        As[ldk + 0][ldr] = av.x; As[ldk + 1][ldr] = av.y;
        As[ldk + 2][ldr] = av.z; As[ldk + 3][ldr] = av.w;
        Bs[ldk + 0][ldr] = bv.x; Bs[ldk + 1][ldr] = bv.y;
        Bs[ldk + 2][ldr] = bv.z; Bs[ldk + 3][ldr] = bv.w;
        __syncthreads();
#pragma unroll
        for (int kk = 0; kk < 16; ++kk) {
            float4 a = *(const float4*)&As[kk][ty * 4];
            float4 b = *(const float4*)&Bs[kk][tx * 4];
            float ar[4] = {a.x, a.y, a.z, a.w};
            float br[4] = {b.x, b.y, b.z, b.w};
#pragma unroll
            for (int i = 0; i < 4; ++i)
#pragma unroll
                for (int j = 0; j < 4; ++j)
                    acc[i][j] = fmaf(ar[i], br[j], acc[i][j]);
        }
    }
    const int n0 = nBase + tx * 4;
    float bias[4];
#pragma unroll
    for (int j = 0; j < 4; ++j) bias[j] = b_ih[n0 + j] + b_hh[n0 + j];
#pragma unroll
    for (int i = 0; i < 4; ++i) {
        const int m = mBase + ty * 4 + i;
        float4 v = {acc[i][0] + bias[0], acc[i][1] + bias[1],
                    acc[i][2] + bias[2], acc[i][3] + bias[3]};
        *(float4*)(out + (size_t)m * 512 + n0) = v;
    }
}

// ---------------------------------------------------------------------------
// Scan v9: EXACTLY the R5 scan7 structure (intrinsic MFMAs -> compiler
// handles all hazards; single h buffer; 2 barriers/step; tau3 in 128 KB LDS)
// with ONE change: tau0..2 W frags are defined by "=a" inline asm, forcing
// them into the AGPR file. Load-remat "spilling" (R4/R5's 384 KB/step L2
// re-stream) is impossible: the defining instruction is the asm, not a load,
// and a real spill would go to scratch (loudly visible). MFMA intrinsics on
// gfx950 read AV-class sources, so AGPR A-operands need no copies.
// ---------------------------------------------------------------------------
__global__
__attribute__((amdgpu_flat_work_group_size(512, 512)))
__attribute__((amdgpu_waves_per_eu(1, 2)))
void rnn_scan9(const __half* __restrict__ whh16,
               const __half* __restrict__ xp16,
               float* __restrict__ out)
{
    __shared__ __align__(16) _Float16 hlds[64 * NB * 8];          // 16 KB
    __shared__ __align__(16) _Float16 alds[8 * 16 * 512];         // 128 KB

    const int bg   = blockIdx.x;
    const int tid  = threadIdx.x;
    const int w    = tid >> 6;
    const int lane = tid & 63;
    const int q    = lane >> 4;
    const int l15  = lane & 15;

    // ---- W fragments: row = 64w + 16*tau + l15, k = 32*ki + 8q + j ----
    const __half* wbase = whh16 + ((size_t)(64 * w + l15)) * 512 + 8 * q;
    half8 wf0[16], wf1[16], wf2[16];
#pragma unroll
    for (int ki = 0; ki < 16; ++ki) {
        half8 v0 = *(const half8*)(wbase + 32 * ki);
        half8 v1 = *(const half8*)(wbase + (size_t)16 * 512 + 32 * ki);
        half8 v2 = *(const half8*)(wbase + (size_t)32 * 512 + 32 * ki);
        asm volatile("" : "=a"(wf0[ki]) : "0"(v0));   // pin to AGPR file
        asm volatile("" : "=a"(wf1[ki]) : "0"(v1));
        asm volatile("" : "=a"(wf2[ki]) : "0"(v2));
    }
    // tau3 -> LDS (per-wave, contiguous 1 KB per (w,ki): conflict-free b128)
#pragma unroll
    for (int ki = 0; ki < 16; ++ki) {
        half8 v = *(const half8*)(wbase + (size_t)48 * 512 + 32 * ki);
        *(half8*)&alds[(w * 16 + ki) * 512 + lane * 8] = v;
    }
    // zero h_0
    {
        float4 z = {0.f, 0.f, 0.f, 0.f};
        *(float4*)&hlds[tid * 16]     = z;
        *(float4*)&hlds[tid * 16 + 8] = z;
    }
    __syncthreads();

    // chunk-layout index for (o = 64w+16*tau+4q+r, batch=l15):
    //   idx = (8w+2*tau+(q>>1))*128 + l15*8 + (q&1)*4 + r    (halfs)
    int cidx[4];
#pragma unroll
    for (int ta = 0; ta < 4; ++ta)
        cidx[ta] = (8 * w + 2 * ta + (q >> 1)) * 128 + l15 * 8 + (q & 1) * 4;

    const __half* xpb = xp16 + (size_t)bg * 8192;   // + t*32768 + cidx[ta]

    // direct out store: batch = bg*16+l15, o = 64w + 16*ta + 4q + r
    float* outr = out + (size_t)(bg * 16 + l15) * 512 + 64 * w + 4 * q;
    const size_t ostride = (size_t)BATCH * HID;

    for (int t = 0; t < T_STEPS; ++t) {
        // xp for this step (consumed in phase B; lives through phase A)
        uint2 xpv0 = *(const uint2*)(xpb + (size_t)t * 32768 + cidx[0]);
        uint2 xpv1 = *(const uint2*)(xpb + (size_t)t * 32768 + cidx[1]);
        uint2 xpv2 = *(const uint2*)(xpb + (size_t)t * 32768 + cidx[2]);
        uint2 xpv3 = *(const uint2*)(xpb + (size_t)t * 32768 + cidx[3]);

        // ---- phase A: 64 MFMA (A from AGPR / LDS) ----
        f32x4 acc0 = {0.f, 0.f, 0.f, 0.f};
        f32x4 acc1 = {0.f, 0.f, 0.f, 0.f};
        f32x4 acc2 = {0.f, 0.f, 0.f, 0.f};
        f32x4 acc3 = {0.f, 0.f, 0.f, 0.f};
#pragma unroll
        for (int ki = 0; ki < 16; ++ki) {
            half8 bfr = *(const half8*)&hlds[(4 * ki + q) * 128 + l15 * 8];
            half8 a3  = *(const half8*)&alds[(w * 16 + ki) * 512 + lane * 8];
            acc0 = __builtin_amdgcn_mfma_f32_16x16x32_f16(wf0[ki], bfr, acc0, 0, 0, 0);
            acc1 = __builtin_amdgcn_mfma_f32_16x16x32_f16(wf1[ki], bfr, acc1, 0, 0, 0);
            acc2 = __builtin_amdgcn_mfma_f32_16x16x32_f16(wf2[ki], bfr, acc2, 0, 0, 0);
            acc3 = __builtin_amdgcn_mfma_f32_16x16x32_f16(a3,      bfr, acc3, 0, 0, 0);
        }
        __syncthreads();   // barrier1: all reads of hlds(h_{t-1}) done

        // ---- phase B: xp add + tanh + h writeback + direct out store ----
#pragma unroll
        for (int ta = 0; ta < 4; ++ta) {
            const uint2 xv = (ta == 0) ? xpv0 : (ta == 1) ? xpv1
                           : (ta == 2) ? xpv2 : xpv3;
            const half4v xh = __builtin_bit_cast(half4v, xv);
            const f32x4 A = (ta == 0) ? acc0 : (ta == 1) ? acc1
                          : (ta == 2) ? acc2 : acc3;
            half4v hv;
            float4 ov;
#pragma unroll
            for (int r = 0; r < 4; ++r) {
                float s = A[r] + (float)xh[r];
                s = fminf(fmaxf(s, -15.f), 15.f);
                const float e = __expf(2.f * s);
                const float hnf = (e - 1.f) * __builtin_amdgcn_rcpf(e + 1.f);
                hv[r] = (_Float16)hnf;
                ov[r] = hnf;
            }
            *(half4v*)&hlds[cidx[ta]] = hv;
            *(float4*)(outr + (size_t)t * ostride + 16 * ta) = ov;
            if (t == T_STEPS - 1)
                *(float4*)(outr + (size_t)T_STEPS * ostride + 16 * ta) = ov;
        }
        __syncthreads();   // barrier2: h_t visible for next step
    }
}

// ---------------------------------------------------------------------------
// Scan v4 (mid-workspace fallback; reads f32 xproj from out in-place).
// ---------------------------------------------------------------------------
#define ACC4(WF, G) do {                                        \
    F4H hh_; hh_.f = *(const float4*)(hrow + (G) * 8);          \
    F4H ww_; ww_.f = (WF);                                      \
    a0 = dot2f(ww_.h[0], hh_.h[0], a0);                         \
    a1 = dot2f(ww_.h[1], hh_.h[1], a1);                         \
    a2 = dot2f(ww_.h[2], hh_.h[2], a2);                         \
    a3 = dot2f(ww_.h[3], hh_.h[3], a3); } while (0)

__global__ __launch_bounds__(512, 2)
void rnn_scan4(const __half* __restrict__ w16, float* __restrict__ out)
{
    __shared__ __align__(16) float4 wlds[SCH_LDS][HID];
    __shared__ __align__(16) __half hbuf[2][HID];

    const int b = blockIdx.x;
    const int j = threadIdx.x;

    const __half* wrow = w16 + (size_t)j * HID;

    float4 wreg[SCH_REG];
#pragma unroll
    for (int c = 0; c < SCH_REG; ++c)
        wreg[c] = *(const float4*)(wrow + c * 8);

#pragma unroll
    for (int c = 0; c < SCH_LDS; ++c)
        wlds[c][j] = *(const float4*)(wrow + (SCH_REG + c) * 8);

    hbuf[0][j] = __float2half(0.f);
    __syncthreads();

    float* outb = out + (size_t)b * HID + j;
    const size_t stride = (size_t)BATCH * HID;
    const __half* wstr = wrow + (SCH_REG + SCH_LDS) * 8;

    int cur = 0;
    float hn = 0.f;
    float xp_next = outb[0];

    for (int t = 0; t < T_STEPS; ++t) {
        const float xp = xp_next;
        const int tn = (t + 1 < T_STEPS) ? (t + 1) : t;
        xp_next = outb[(size_t)tn * stride];

        const __half* hrow = hbuf[cur];

        float4 wa[SCH_SA];
#pragma unroll
        for (int c = 0; c < SCH_SA; ++c)
            wa[c] = *(const float4*)(wstr + c * 8);

        float a0 = xp, a1 = 0.f, a2 = 0.f, a3 = 0.f;

#pragma unroll
        for (int c = 0; c < 20; ++c) ACC4(wreg[c], c);
#pragma unroll
        for (int c = 0; c < SCH_SA; ++c)
            ACC4(wa[c], SCH_REG + SCH_LDS + c);

        float4 wb[SCH_SB];
#pragma unroll
        for (int c = 0; c < SCH_SB; ++c)
            wb[c] = *(const float4*)(wstr + (SCH_SA + c) * 8);

#pragma unroll
        for (int c = 20; c < SCH_REG; ++c) ACC4(wreg[c], c);
#pragma unroll
        for (int c = 0; c < SCH_LDS; ++c) {
            float4 wfv = wlds[c][j];
            ACC4(wfv, SCH_REG + c);
        }

#pragma unroll
        for (int c = 0; c < SCH_SB; ++c)
            ACC4(wb[c], SCH_REG + SCH_LDS + SCH_SA + c);

        float s = (a0 + a1) + (a2 + a3);
        s = fminf(fmaxf(s, -15.f), 15.f);
        const float e = __expf(2.f * s);
        hn = (e - 1.f) * __builtin_amdgcn_rcpf(e + 1.f);

        outb[(size_t)t * stride] = hn;
        hbuf[cur ^ 1][j] = __float2half(hn);
        __syncthreads();
        cur ^= 1;
    }
    out[(size_t)T_STEPS * stride + (size_t)b * HID + j] = hn;
}

// ---------------------------------------------------------------------------
// Last-resort fp32 scan (no workspace needed).
// ---------------------------------------------------------------------------
__global__ __launch_bounds__(512) void rnn_scan_f32(const float* __restrict__ w,
                                                    float* __restrict__ out)
{
    __shared__ __align__(16) __half hs[2][HID];
    const int b = blockIdx.x;
    const int j = threadIdx.x;

    hs[0][j] = __float2half(0.f);
    __syncthreads();

    const float* wrow32 = w + (size_t)j * HID;
    float* outb = out + (size_t)b * HID + j;
    int cur = 0;
    float hn = 0.f;

    for (int t = 0; t < T_STEPS; ++t) {
        float a0 = outb[(size_t)t * (BATCH * HID)];
        float a1 = 0.f, a2 = 0.f, a3 = 0.f;
#pragma unroll 4
        for (int k0 = 0; k0 < HID; k0 += 8) {
            float4 w0 = *(const float4*)(wrow32 + k0);
            float4 w1 = *(const float4*)(wrow32 + k0 + 4);
            F4H h; h.f = *(const float4*)(&hs[cur][k0]);
            float2 h0 = __half22float2(*(__half2*)&h.h[0]);
            float2 h1 = __half22float2(*(__half2*)&h.h[1]);
            float2 h2 = __half22float2(*(__half2*)&h.h[2]);
            float2 h3 = __half22float2(*(__half2*)&h.h[3]);
            a0 = fmaf(w0.x, h0.x, a0); a1 = fmaf(w0.y, h0.y, a1);
            a2 = fmaf(w0.z, h1.x, a2); a3 = fmaf(w0.w, h1.y, a3);
            a0 = fmaf(w1.x, h2.x, a0); a1 = fmaf(w1.y, h2.y, a1);
            a2 = fmaf(w1.z, h3.x, a2); a3 = fmaf(w1.w, h3.y, a3);
        }
        hn = tanhf((a0 + a1) + (a2 + a3));
        outb[(size_t)t * (BATCH * HID)] = hn;
        hs[cur ^ 1][j] = __float2half(hn);
        __syncthreads();
        cur ^= 1;
    }
    out[(size_t)T_STEPS * BATCH * HID + (size_t)b * HID + j] = hn;
}

// ---------------------------------------------------------------------------
extern "C" void kernel_launch(void* const* d_in, const int* in_sizes, int n_in,
                              void* d_out, int out_size, void* d_ws, size_t ws_size,
                              hipStream_t stream) {
    const float* x    = (const float*)d_in[0];
    const float* w_ih = (const float*)d_in[1];
    const float* w_hh = (const float*)d_in[2];
    const float* b_ih = (const float*)d_in[3];
    const float* b_hh = (const float*)d_in[4];
    float* out = (float*)d_out;

    char* ws = (char*)d_ws;
    const bool full = ws_size >= (size_t)WS_FULL;
    const bool mid  = ws_size >= (size_t)WHH_BYTES;

    if (full) {
        __half*         xp16  = (__half*)(ws + XP16_OFF);
        unsigned short* wih16 = (unsigned short*)(ws + WIH_OFF);
        __half*         whh16 = (__half*)(ws + WHH_OFF);
        cvt_bf16<<<256, 256, 0, stream>>>(w_ih, wih16);
        cvt_f16 <<<256, 256, 0, stream>>>(w_hh, whh16);
        xproj_mfma<<<dim3(4, 256), 256, 0, stream>>>(x, wih16, b_ih, b_hh, xp16);
        rnn_scan9<<<4, 512, 0, stream>>>(whh16, xp16, out);
    } else if (mid) {
        __half* whh16 = (__half*)ws;
        cvt_f16<<<256, 256, 0, stream>>>(w_hh, whh16);
        xproj_gemm<<<dim3(8, 512), 256, 0, stream>>>(x, w_ih, b_ih, b_hh, out);
        rnn_scan4<<<BATCH, HID, 0, stream>>>(whh16, out);
    } else {
        xproj_gemm<<<dim3(8, 512), 256, 0, stream>>>(x, w_ih, b_ih, b_hh, out);
        rnn_scan_f32<<<BATCH, HID, 0, stream>>>(w_hh, out);
    }
}

// Round 9
// 1185.374 us; speedup vs baseline: 3.9081x; 1.0110x over previous
//
#include <hip/hip_runtime.h>
#include <hip/hip_fp16.h>

#define T_STEPS 512
#define BATCH   64
#define HID     512

// ---- scan10 geometry: grid=4 blocks x 16 batches, 8 waves x 64 rows ----
// Per-wave W = 64 frag-sets (tau 0..3 x ki 0..15), 16B/lane each.
// HARD CONSTRAINT (R7 post-mortem): 8-wave block => 2 waves/SIMD => 256
// regs/wave TOTAL (V+A). So W can NEVER be fully register-resident.
// Split: 24 sets AGPR (96 regs, FEASIBLE ask) + 15 sets LDS (120 KB)
//        + 25 sets streamed from L2 per step (200 KB, was 384 KB).
// h double-buffered (2 x 16 KB) -> ONE barrier/step (waves drift; VALU
// of one wave overlaps MFMA of the other).
#define NB      16
#define ALD     15                  // tau3 ki0..14 in LDS

// ---- scan4 (fallback) W-row split ----
#define SCH_REG  40
#define SCH_LDS  10
#define SCH_SA   7
#define SCH_SB   7

// Workspace layout (unchanged, ~34.6 MB):
#define XP16_OFF  0u
#define XP16_BYTES (16777216u * 2u)         // 32 MB f16 xp (chunk layout)
#define WIH_OFF   (XP16_OFF + XP16_BYTES)
#define WIH_BYTES (262144u * 2u)
#define WHH_OFF   (WIH_OFF + WIH_BYTES)
#define WHH_BYTES (262144u * 2u)
#define WS_FULL   (WHH_OFF + WHH_BYTES)

typedef _Float16 half2v  __attribute__((ext_vector_type(2)));
typedef _Float16 half4v  __attribute__((ext_vector_type(4)));
typedef _Float16 half8   __attribute__((ext_vector_type(8)));
typedef short    short8  __attribute__((ext_vector_type(8)));
typedef float    f32x4   __attribute__((ext_vector_type(4)));
union F4H  { float4 f; half2v h[4]; };

__device__ inline float dot2f(half2v a, half2v b, float c) {
    return __builtin_amdgcn_fdot2(a, b, c, false);
}
__device__ inline unsigned short f2bf(float f) {
    unsigned u = __builtin_bit_cast(unsigned, f);
    return (unsigned short)((u + 0x7FFFu + ((u >> 16) & 1u)) >> 16);
}

// Streamed-set schedules (compile-time; fully unrolled => constant indices).
// Batch A: tau0 ki8..15 (8) + tau1 ki8..12 (5) = 13
// Batch B: tau1 ki13..15 (3) + tau2 ki8..15 (8) + tau3 ki15 (1) = 12
__device__ constexpr int SA_T[13] = {0,0,0,0,0,0,0,0, 1,1,1,1,1};
__device__ constexpr int SA_K[13] = {8,9,10,11,12,13,14,15, 8,9,10,11,12};
__device__ constexpr int SB_T[12] = {1,1,1, 2,2,2,2,2,2,2,2, 3};
__device__ constexpr int SB_K[12] = {13,14,15, 8,9,10,11,12,13,14,15, 15};

// ---------------------------------------------------------------------------
// Conversions (re-run every call; ws is re-poisoned by the harness).
// ---------------------------------------------------------------------------
__global__ __launch_bounds__(256) void cvt_f16(const float* __restrict__ w,
                                               __half* __restrict__ o) {
    const int i = (blockIdx.x * 256 + threadIdx.x) * 4;
    float4 v = *(const float4*)(w + i);
    __half2 p0; p0.x = __float2half(v.x); p0.y = __float2half(v.y);
    __half2 p1; p1.x = __float2half(v.z); p1.y = __float2half(v.w);
    *(__half2*)(o + i)     = p0;
    *(__half2*)(o + i + 2) = p1;
}

__global__ __launch_bounds__(256) void cvt_bf16(const float* __restrict__ s,
                                                unsigned short* __restrict__ o) {
    const int i = (blockIdx.x * 256 + threadIdx.x) * 4;
    float4 v = *(const float4*)(s + i);
    ushort4 r = {f2bf(v.x), f2bf(v.y), f2bf(v.z), f2bf(v.w)};
    *(ushort4*)(o + i) = r;
}

// ---------------------------------------------------------------------------
// xproj via bf16 MFMA. Reads x f32 (converts in staging), writes f16 xp16
// in the scan's chunk layout:
//   half-index(t,b,o) = t*32768 + (b>>4)*8192 + (o>>3)*128 + (b&15)*8 + (o&7)
// ---------------------------------------------------------------------------
__global__ __launch_bounds__(256) void xproj_mfma(
    const float* __restrict__ x,
    const unsigned short* __restrict__ w16,
    const float* __restrict__ b_ih, const float* __restrict__ b_hh,
    __half* __restrict__ xp16)
{
    __shared__ __align__(16) unsigned short As[128][40];
    __shared__ __align__(16) unsigned short Bs[128][40];

    const int tid   = threadIdx.x;
    const int mBase = blockIdx.y * 128;
    const int nBase = blockIdx.x * 128;
    const int wave  = tid >> 6, lane = tid & 63;
    const int wy    = wave >> 1, wx = wave & 1;
    const int quad  = lane >> 4, l15 = lane & 15;
    const int lr    = tid >> 2;
    const int lk    = (tid & 3) * 8;

    f32x4 acc[4][4] = {};

    const size_t arow0 = (size_t)(mBase + lr) * 512 + lk;
    const size_t brow0 = (size_t)(nBase + lr) * 512 + lk;

    for (int k0 = 0; k0 < 512; k0 += 32) {
        float4 a0l = *(const float4*)(x + arow0 + k0);
        float4 a0h = *(const float4*)(x + arow0 + k0 + 4);
        float4 a1l = *(const float4*)(x + arow0 + (size_t)64 * 512 + k0);
        float4 a1h = *(const float4*)(x + arow0 + (size_t)64 * 512 + k0 + 4);
        int4 b0 = *(const int4*)(w16 + brow0 + k0);
        int4 b1 = *(const int4*)(w16 + brow0 + (size_t)64 * 512 + k0);
        int4 A0, A1;
        A0.x = f2bf(a0l.x) | ((unsigned)f2bf(a0l.y) << 16);
        A0.y = f2bf(a0l.z) | ((unsigned)f2bf(a0l.w) << 16);
        A0.z = f2bf(a0h.x) | ((unsigned)f2bf(a0h.y) << 16);
        A0.w = f2bf(a0h.z) | ((unsigned)f2bf(a0h.w) << 16);
        A1.x = f2bf(a1l.x) | ((unsigned)f2bf(a1l.y) << 16);
        A1.y = f2bf(a1l.z) | ((unsigned)f2bf(a1l.w) << 16);
        A1.z = f2bf(a1h.x) | ((unsigned)f2bf(a1h.y) << 16);
        A1.w = f2bf(a1h.z) | ((unsigned)f2bf(a1h.w) << 16);
        __syncthreads();
        *(int4*)&As[lr][lk]      = A0;
        *(int4*)&As[lr + 64][lk] = A1;
        *(int4*)&Bs[lr][lk]      = b0;
        *(int4*)&Bs[lr + 64][lk] = b1;
        __syncthreads();

        short8 af[4], bf[4];
#pragma unroll
        for (int mt = 0; mt < 4; ++mt)
            af[mt] = *(const short8*)&As[wy * 64 + mt * 16 + l15][quad * 8];
#pragma unroll
        for (int nt = 0; nt < 4; ++nt)
            bf[nt] = *(const short8*)&Bs[wx * 64 + nt * 16 + l15][quad * 8];
#pragma unroll
        for (int mt = 0; mt < 4; ++mt)
#pragma unroll
            for (int nt = 0; nt < 4; ++nt)
                acc[mt][nt] = __builtin_amdgcn_mfma_f32_16x16x32_bf16(
                    af[mt], bf[nt], acc[mt][nt], 0, 0, 0);
    }

    float bias[4]; int coln[4];
#pragma unroll
    for (int nt = 0; nt < 4; ++nt) {
        coln[nt] = nBase + wx * 64 + nt * 16 + l15;
        bias[nt] = b_ih[coln[nt]] + b_hh[coln[nt]];
    }
#pragma unroll
    for (int mt = 0; mt < 4; ++mt)
#pragma unroll
        for (int r = 0; r < 4; ++r) {
            const int m = mBase + wy * 64 + mt * 16 + quad * 4 + r;
            const int tt = m >> 6, b = m & 63;
#pragma unroll
            for (int nt = 0; nt < 4; ++nt) {
                const int o = coln[nt];
                const size_t idx = (size_t)tt * 32768 + (size_t)(b >> 4) * 8192
                                 + (o >> 3) * 128 + (b & 15) * 8 + (o & 7);
                xp16[idx] = __float2half(acc[mt][nt][r] + bias[nt]);
            }
        }
}

// ---------------------------------------------------------------------------
// Fallback fp32 xproj (writes f32 xproj into out, scan4-compatible).
// ---------------------------------------------------------------------------
__global__ __launch_bounds__(256) void xproj_gemm(
    const float* __restrict__ x, const float* __restrict__ w_ih,
    const float* __restrict__ b_ih, const float* __restrict__ b_hh,
    float* __restrict__ out)
{
    __shared__ __align__(16) float As[16][68];
    __shared__ __align__(16) float Bs[16][68];

    const int tid   = threadIdx.x;
    const int tx    = tid & 15;
    const int ty    = tid >> 4;
    const int mBase = blockIdx.y * 64;
    const int nBase = blockIdx.x * 64;
    const int ldr   = tid >> 2;
    const int ldk   = (tid & 3) * 4;

    float acc[4][4] = {};
    const float* aptr = x    + (size_t)(mBase + ldr) * 512 + ldk;
    const float* bptr = w_ih + (size_t)(nBase + ldr) * 512 + ldk;

    for (int k0 = 0; k0 < 512; k0 += 16) {
        float4 av = *(const float4*)(aptr + k0);
        float4 bv = *(const float4*)(bptr + k0);
        __syncthreads();
        As[ldk + 0][ldr] = av.x; As[ldk + 1][ldr] = av.y;
        As[ldk + 2][ldr] = av.z; As[ldk + 3][ldr] = av.w;
        Bs[ldk + 0][ldr] = bv.x; Bs[ldk + 1][ldr] = bv.y;
        Bs[ldk + 2][ldr] = bv.z; Bs[ldk + 3][ldr] = bv.w;
        __syncthreads();
#pragma unroll
        for (int kk = 0; kk < 16; ++kk) {
            float4 a = *(const float4*)&As[kk][ty * 4];
            float4 b = *(const float4*)&Bs[kk][tx * 4];
            float ar[4] = {a.x, a.y, a.z, a.w};
            float br[4] = {b.x, b.y, b.z, b.w};
#pragma unroll
            for (int i = 0; i < 4; ++i)
#pragma unroll
                for (int j = 0; j < 4; ++j)
                    acc[i][j] = fmaf(ar[i], br[j], acc[i][j]);
        }
    }
    const int n0 = nBase + tx * 4;
    float bias[4];
#pragma unroll
    for (int j = 0; j < 4; ++j) bias[j] = b_ih[n0 + j] + b_hh[n0 + j];
#pragma unroll
    for (int i = 0; i < 4; ++i) {
        const int m = mBase + ty * 4 + i;
        float4 v = {acc[i][0] + bias[0], acc[i][1] + bias[1],
                    acc[i][2] + bias[2], acc[i][3] + bias[3]};
        *(float4*)(out + (size_t)m * 512 + n0) = v;
    }
}

// ---------------------------------------------------------------------------
// Scan v10: feasible W split + single-barrier pipelined step.
//   24 sets AGPR-pinned (96 regs; fits the 256/wave HARD cap at 2 waves/SIMD)
//   15 sets LDS (120 KB) ; 25 sets streamed from L2 in 2 batches per step.
//   h double-buffered (2 x 16 KB; LDS total 152 KB) -> ONE barrier/step.
//   MFMA via intrinsics (compiler hazards, proven R7); AGPR pin proven R7.
// ---------------------------------------------------------------------------
__global__
__attribute__((amdgpu_flat_work_group_size(512, 512)))
__attribute__((amdgpu_waves_per_eu(1, 2)))
void rnn_scan10(const __half* __restrict__ whh16,
                const __half* __restrict__ xp16,
                float* __restrict__ out)
{
    __shared__ __align__(16) _Float16 hlds[2][64 * NB * 8];       // 32 KB
    __shared__ __align__(16) _Float16 alds[8 * ALD * 512];        // 120 KB

    const int bg   = blockIdx.x;
    const int tid  = threadIdx.x;
    const int w    = tid >> 6;
    const int lane = tid & 63;
    const int q    = lane >> 4;
    const int l15  = lane & 15;

    // ---- W fragments: row = 64w + 16*tau + l15, k = 32*ki + 8q + j ----
    const __half* wbase = whh16 + ((size_t)(64 * w + l15)) * 512 + 8 * q;

    // 24 sets -> AGPR (tau 0..2, ki 0..7). Feasible: 96 A + ~130 V < 256.
    half8 wA[24];
#pragma unroll
    for (int ta = 0; ta < 3; ++ta)
#pragma unroll
        for (int ki = 0; ki < 8; ++ki) {
            half8 v = *(const half8*)(wbase + (size_t)(16 * ta) * 512 + 32 * ki);
            asm volatile("" : "=a"(wA[ta * 8 + ki]) : "0"(v));
        }
    // 15 sets -> LDS (tau3 ki0..14), per-wave contiguous 1 KB: conflict-free
#pragma unroll
    for (int ki = 0; ki < ALD; ++ki) {
        half8 v = *(const half8*)(wbase + (size_t)48 * 512 + 32 * ki);
        *(half8*)&alds[(w * ALD + ki) * 512 + lane * 8] = v;
    }
    // zero h_0 into buffer 0
    {
        float4 z = {0.f, 0.f, 0.f, 0.f};
        *(float4*)&hlds[0][tid * 16]     = z;
        *(float4*)&hlds[0][tid * 16 + 8] = z;
    }
    __syncthreads();

    // chunk-layout index for (o = 64w+16*tau+4q+r, batch=l15):
    //   idx = (8w+2*tau+(q>>1))*128 + l15*8 + (q&1)*4 + r    (halfs)
    int cidx[4];
#pragma unroll
    for (int ta = 0; ta < 4; ++ta)
        cidx[ta] = (8 * w + 2 * ta + (q >> 1)) * 128 + l15 * 8 + (q & 1) * 4;

    const __half* xpb = xp16 + (size_t)bg * 8192;   // + t*32768 + cidx[ta]

    // direct out store: batch = bg*16+l15, o = 64w + 16*ta + 4q + r
    float* outr = out + (size_t)(bg * 16 + l15) * 512 + 64 * w + 4 * q;
    const size_t ostride = (size_t)BATCH * HID;

    for (int t = 0; t < T_STEPS; ++t) {
        const _Float16* hread  = hlds[t & 1];
        _Float16*       hwrite = hlds[(t & 1) ^ 1];

        // xp for this step (consumed in phase B; latency hides under MFMA)
        uint2 xpv0 = *(const uint2*)(xpb + (size_t)t * 32768 + cidx[0]);
        uint2 xpv1 = *(const uint2*)(xpb + (size_t)t * 32768 + cidx[1]);
        uint2 xpv2 = *(const uint2*)(xpb + (size_t)t * 32768 + cidx[2]);
        uint2 xpv3 = *(const uint2*)(xpb + (size_t)t * 32768 + cidx[3]);

        // issue stream batch A (13 sets; consumed after 39 MFMAs)
        half8 sA[13];
#pragma unroll
        for (int i = 0; i < 13; ++i)
            sA[i] = *(const half8*)(wbase + (size_t)(16 * SA_T[i]) * 512
                                          + 32 * SA_K[i]);

        f32x4 acc[4] = {{0.f,0.f,0.f,0.f}, {0.f,0.f,0.f,0.f},
                        {0.f,0.f,0.f,0.f}, {0.f,0.f,0.f,0.f}};

        // ---- AGPR sets: tau0..2, ki0..7 (24 MFMA) ----
#pragma unroll
        for (int ki = 0; ki < 8; ++ki) {
            half8 bfr = *(const half8*)&hread[(4 * ki + q) * 128 + l15 * 8];
            acc[0] = __builtin_amdgcn_mfma_f32_16x16x32_f16(wA[ki],      bfr, acc[0], 0, 0, 0);
            acc[1] = __builtin_amdgcn_mfma_f32_16x16x32_f16(wA[8 + ki],  bfr, acc[1], 0, 0, 0);
            acc[2] = __builtin_amdgcn_mfma_f32_16x16x32_f16(wA[16 + ki], bfr, acc[2], 0, 0, 0);
        }
        // ---- LDS sets: tau3, ki0..14 (15 MFMA) ----
#pragma unroll
        for (int ki = 0; ki < ALD; ++ki) {
            half8 bfr = *(const half8*)&hread[(4 * ki + q) * 128 + l15 * 8];
            half8 a3  = *(const half8*)&alds[(w * ALD + ki) * 512 + lane * 8];
            acc[3] = __builtin_amdgcn_mfma_f32_16x16x32_f16(a3, bfr, acc[3], 0, 0, 0);
        }
        // ---- consume batch A (13 MFMA) ----
#pragma unroll
        for (int i = 0; i < 13; ++i) {
            half8 bfr = *(const half8*)&hread[(4 * SA_K[i] + q) * 128 + l15 * 8];
            acc[SA_T[i]] = __builtin_amdgcn_mfma_f32_16x16x32_f16(
                sA[i], bfr, acc[SA_T[i]], 0, 0, 0);
        }
        // issue + consume batch B (12 sets; latency covered by A-consumption
        // MFMAs still in flight and the B-issue/first-consume gap)
        half8 sB[12];
#pragma unroll
        for (int i = 0; i < 12; ++i)
            sB[i] = *(const half8*)(wbase + (size_t)(16 * SB_T[i]) * 512
                                          + 32 * SB_K[i]);
#pragma unroll
        for (int i = 0; i < 12; ++i) {
            half8 bfr = *(const half8*)&hread[(4 * SB_K[i] + q) * 128 + l15 * 8];
            acc[SB_T[i]] = __builtin_amdgcn_mfma_f32_16x16x32_f16(
                sB[i], bfr, acc[SB_T[i]], 0, 0, 0);
        }

        // keep the AGPR W pinned across iterations (anti-evict, 0 instr)
        asm volatile("" : "+a"(wA[0]),  "+a"(wA[1]),  "+a"(wA[2]),  "+a"(wA[3]),
                          "+a"(wA[4]),  "+a"(wA[5]),  "+a"(wA[6]),  "+a"(wA[7]),
                          "+a"(wA[8]),  "+a"(wA[9]),  "+a"(wA[10]), "+a"(wA[11]));
        asm volatile("" : "+a"(wA[12]), "+a"(wA[13]), "+a"(wA[14]), "+a"(wA[15]),
                          "+a"(wA[16]), "+a"(wA[17]), "+a"(wA[18]), "+a"(wA[19]),
                          "+a"(wA[20]), "+a"(wA[21]), "+a"(wA[22]), "+a"(wA[23]));

        // ---- phase B: xp add + tanh + h write (OTHER buffer) + out store ----
#pragma unroll
        for (int ta = 0; ta < 4; ++ta) {
            const uint2 xv = (ta == 0) ? xpv0 : (ta == 1) ? xpv1
                           : (ta == 2) ? xpv2 : xpv3;
            const half4v xh = __builtin_bit_cast(half4v, xv);
            half4v hv;
            float4 ov;
#pragma unroll
            for (int r = 0; r < 4; ++r) {
                float s = acc[ta][r] + (float)xh[r];
                s = fminf(fmaxf(s, -15.f), 15.f);
                const float e = __expf(2.f * s);
                const float hnf = (e - 1.f) * __builtin_amdgcn_rcpf(e + 1.f);
                hv[r] = (_Float16)hnf;
                ov[r] = hnf;
            }
            *(half4v*)&hwrite[cidx[ta]] = hv;
            *(float4*)(outr + (size_t)t * ostride + 16 * ta) = ov;
            if (t == T_STEPS - 1)
                *(float4*)(outr + (size_t)T_STEPS * ostride + 16 * ta) = ov;
        }
        __syncthreads();   // single barrier/step: h_t visible for next read
    }
}

// ---------------------------------------------------------------------------
// Scan v4 (mid-workspace fallback; reads f32 xproj from out in-place).
// ---------------------------------------------------------------------------
#define ACC4(WF, G) do {                                        \
    F4H hh_; hh_.f = *(const float4*)(hrow + (G) * 8);          \
    F4H ww_; ww_.f = (WF);                                      \
    a0 = dot2f(ww_.h[0], hh_.h[0], a0);                         \
    a1 = dot2f(ww_.h[1], hh_.h[1], a1);                         \
    a2 = dot2f(ww_.h[2], hh_.h[2], a2);                         \
    a3 = dot2f(ww_.h[3], hh_.h[3], a3); } while (0)

__global__ __launch_bounds__(512, 2)
void rnn_scan4(const __half* __restrict__ w16, float* __restrict__ out)
{
    __shared__ __align__(16) float4 wlds[SCH_LDS][HID];
    __shared__ __align__(16) __half hbuf[2][HID];

    const int b = blockIdx.x;
    const int j = threadIdx.x;

    const __half* wrow = w16 + (size_t)j * HID;

    float4 wreg[SCH_REG];
#pragma unroll
    for (int c = 0; c < SCH_REG; ++c)
        wreg[c] = *(const float4*)(wrow + c * 8);

#pragma unroll
    for (int c = 0; c < SCH_LDS; ++c)
        wlds[c][j] = *(const float4*)(wrow + (SCH_REG + c) * 8);

    hbuf[0][j] = __float2half(0.f);
    __syncthreads();

    float* outb = out + (size_t)b * HID + j;
    const size_t stride = (size_t)BATCH * HID;
    const __half* wstr = wrow + (SCH_REG + SCH_LDS) * 8;

    int cur = 0;
    float hn = 0.f;
    float xp_next = outb[0];

    for (int t = 0; t < T_STEPS; ++t) {
        const float xp = xp_next;
        const int tn = (t + 1 < T_STEPS) ? (t + 1) : t;
        xp_next = outb[(size_t)tn * stride];

        const __half* hrow = hbuf[cur];

        float4 wa[SCH_SA];
#pragma unroll
        for (int c = 0; c < SCH_SA; ++c)
            wa[c] = *(const float4*)(wstr + c * 8);

        float a0 = xp, a1 = 0.f, a2 = 0.f, a3 = 0.f;

#pragma unroll
        for (int c = 0; c < 20; ++c) ACC4(wreg[c], c);
#pragma unroll
        for (int c = 0; c < SCH_SA; ++c)
            ACC4(wa[c], SCH_REG + SCH_LDS + c);

        float4 wb[SCH_SB];
#pragma unroll
        for (int c = 0; c < SCH_SB; ++c)
            wb[c] = *(const float4*)(wstr + (SCH_SA + c) * 8);

#pragma unroll
        for (int c = 20; c < SCH_REG; ++c) ACC4(wreg[c], c);
#pragma unroll
        for (int c = 0; c < SCH_LDS; ++c) {
            float4 wfv = wlds[c][j];
            ACC4(wfv, SCH_REG + c);
        }

#pragma unroll
        for (int c = 0; c < SCH_SB; ++c)
            ACC4(wb[c], SCH_REG + SCH_LDS + SCH_SA + c);

        float s = (a0 + a1) + (a2 + a3);
        s = fminf(fmaxf(s, -15.f), 15.f);
        const float e = __expf(2.f * s);
        hn = (e - 1.f) * __builtin_amdgcn_rcpf(e + 1.f);

        outb[(size_t)t * stride] = hn;
        hbuf[cur ^ 1][j] = __float2half(hn);
        __syncthreads();
        cur ^= 1;
    }
    out[(size_t)T_STEPS * stride + (size_t)b * HID + j] = hn;
}

// ---------------------------------------------------------------------------
// Last-resort fp32 scan (no workspace needed).
// ---------------------------------------------------------------------------
__global__ __launch_bounds__(512) void rnn_scan_f32(const float* __restrict__ w,
                                                    float* __restrict__ out)
{
    __shared__ __align__(16) __half hs[2][HID];
    const int b = blockIdx.x;
    const int j = threadIdx.x;

    hs[0][j] = __float2half(0.f);
    __syncthreads();

    const float* wrow32 = w + (size_t)j * HID;
    float* outb = out + (size_t)b * HID + j;
    int cur = 0;
    float hn = 0.f;

    for (int t = 0; t < T_STEPS; ++t) {
        float a0 = outb[(size_t)t * (BATCH * HID)];
        float a1 = 0.f, a2 = 0.f, a3 = 0.f;
#pragma unroll 4
        for (int k0 = 0; k0 < HID; k0 += 8) {
            float4 w0 = *(const float4*)(wrow32 + k0);
            float4 w1 = *(const float4*)(wrow32 + k0 + 4);
            F4H h; h.f = *(const float4*)(&hs[cur][k0]);
            float2 h0 = __half22float2(*(__half2*)&h.h[0]);
            float2 h1 = __half22float2(*(__half2*)&h.h[1]);
            float2 h2 = __half22float2(*(__half2*)&h.h[2]);
            float2 h3 = __half22float2(*(__half2*)&h.h[3]);
            a0 = fmaf(w0.x, h0.x, a0); a1 = fmaf(w0.y, h0.y, a1);
            a2 = fmaf(w0.z, h1.x, a2); a3 = fmaf(w0.w, h1.y, a3);
            a0 = fmaf(w1.x, h2.x, a0); a1 = fmaf(w1.y, h2.y, a1);
            a2 = fmaf(w1.z, h3.x, a2); a3 = fmaf(w1.w, h3.y, a3);
        }
        hn = tanhf((a0 + a1) + (a2 + a3));
        outb[(size_t)t * (BATCH * HID)] = hn;
        hs[cur ^ 1][j] = __float2half(hn);
        __syncthreads();
        cur ^= 1;
    }
    out[(size_t)T_STEPS * BATCH * HID + (size_t)b * HID + j] = hn;
}

// ---------------------------------------------------------------------------
extern "C" void kernel_launch(void* const* d_in, const int* in_sizes, int n_in,
                              void* d_out, int out_size, void* d_ws, size_t ws_size,
                              hipStream_t stream) {
    const float* x    = (const float*)d_in[0];
    const float* w_ih = (const float*)d_in[1];
    const float* w_hh = (const float*)d_in[2];
    const float* b_ih = (const float*)d_in[3];
    const float* b_hh = (const float*)d_in[4];
    float* out = (float*)d_out;

    char* ws = (char*)d_ws;
    const bool full = ws_size >= (size_t)WS_FULL;
    const bool mid  = ws_size >= (size_t)WHH_BYTES;

    if (full) {
        __half*         xp16  = (__half*)(ws + XP16_OFF);
        unsigned short* wih16 = (unsigned short*)(ws + WIH_OFF);
        __half*         whh16 = (__half*)(ws + WHH_OFF);
        cvt_bf16<<<256, 256, 0, stream>>>(w_ih, wih16);
        cvt_f16 <<<256, 256, 0, stream>>>(w_hh, whh16);
        xproj_mfma<<<dim3(4, 256), 256, 0, stream>>>(x, wih16, b_ih, b_hh, xp16);
        rnn_scan10<<<4, 512, 0, stream>>>(whh16, xp16, out);
    } else if (mid) {
        __half* whh16 = (__half*)ws;
        cvt_f16<<<256, 256, 0, stream>>>(w_hh, whh16);
        xproj_gemm<<<dim3(8, 512), 256, 0, stream>>>(x, w_ih, b_ih, b_hh, out);
        rnn_scan4<<<BATCH, HID, 0, stream>>>(whh16, out);
    } else {
        xproj_gemm<<<dim3(8, 512), 256, 0, stream>>>(x, w_ih, b_ih, b_hh, out);
        rnn_scan_f32<<<BATCH, HID, 0, stream>>>(w_hh, out);
    }
}